// Round 1
// baseline (18296.776 us; speedup 1.0000x reference)
//
#include <hip/hip_runtime.h>
#include <cstddef>
#include <cstdint>

// Problem constants
#define BN 64
#define LN 128
#define TN 32
#define HN 512
#define GN 2048  // 4*H

// ---------------- workspace layout (float offsets) ----------------
// WtE  [512][2048]  Whh_e transposed (k-major)          1048576
// WtD  [512][2048]  Whh_d transposed                    1048576
// WeT  [512][512]   We transposed ((We.T)[m][j])         262144
// WdT  [512][512]   Wd transposed                        262144
// M0   [512][512]   M ping                               262144
// M1   [512][512]   M pong                               262144
// cv0  [512]        c_i ping
// cv1  [512]        c_i pong
// bsE  [2048]       bih_e+bhh_e
// bsD  [2048]       bih_d+bhh_d
// e    [64][128][512]  encoder h_all (B,L,H)            4194304
// ecur [64][128][512]  current e_cur_i                  4194304
// hdec [64][512], cdec [64][512], dbuf[64]
static const size_t off_WtE  = 0;
static const size_t off_WtD  = off_WtE + (size_t)HN*GN;
static const size_t off_WeT  = off_WtD + (size_t)HN*GN;
static const size_t off_WdT  = off_WeT + (size_t)HN*HN;
static const size_t off_M0   = off_WdT + (size_t)HN*HN;
static const size_t off_M1   = off_M0  + (size_t)HN*HN;
static const size_t off_cv0  = off_M1  + (size_t)HN*HN;
static const size_t off_cv1  = off_cv0 + HN;
static const size_t off_bsE  = off_cv1 + HN;
static const size_t off_bsD  = off_bsE + GN;
static const size_t off_e    = off_bsD + GN;
static const size_t off_ecur = off_e    + (size_t)BN*LN*HN;
static const size_t off_hdec = off_ecur + (size_t)BN*LN*HN;
static const size_t off_cdec = off_hdec + (size_t)BN*HN;
static const size_t off_dbuf = off_cdec + (size_t)BN*HN;

__device__ __forceinline__ float fsig(float x)  { return 1.0f / (1.0f + __expf(-x)); }
__device__ __forceinline__ float ftanh(float x) { return 1.0f - 2.0f / (__expf(2.0f * x) + 1.0f); }

// ---------------- prep: transposes + bias sums + chain init ----------------
__global__ __launch_bounds__(256) void k_prep(
    const float* __restrict__ Whh_e, const float* __restrict__ Whh_d,
    const float* __restrict__ We,    const float* __restrict__ Wd,
    const float* __restrict__ bih_e, const float* __restrict__ bhh_e,
    const float* __restrict__ bih_d, const float* __restrict__ bhh_d,
    const float* __restrict__ be,
    float* __restrict__ WtE, float* __restrict__ WtD,
    float* __restrict__ WeT, float* __restrict__ M0, float* __restrict__ WdT,
    float* __restrict__ bsE, float* __restrict__ bsD, float* __restrict__ cv0) {
  const size_t S1 = 1048576, S2 = 2097152, S3 = 2359296, S4 = 2621440,
               S5 = 2623488, S6 = 2625536, S7 = 2626048;
  size_t stride = (size_t)gridDim.x * blockDim.x;
  for (size_t idx = (size_t)blockIdx.x * blockDim.x + threadIdx.x; idx < S7; idx += stride) {
    if (idx < S1) {
      size_t k = idx >> 11, j = idx & 2047;
      WtE[idx] = Whh_e[j * 512 + k];
    } else if (idx < S2) {
      size_t r = idx - S1, k = r >> 11, j = r & 2047;
      WtD[r] = Whh_d[j * 512 + k];
    } else if (idx < S3) {
      size_t r = idx - S2, m = r >> 9, j = r & 511;
      float vv = We[j * 512 + m];
      WeT[r] = vv; M0[r] = vv;
    } else if (idx < S4) {
      size_t r = idx - S3, m = r >> 9, j = r & 511;
      WdT[r] = Wd[j * 512 + m];
    } else if (idx < S5) {
      size_t r = idx - S4;
      bsE[r] = bih_e[r] + bhh_e[r];
    } else if (idx < S6) {
      size_t r = idx - S5;
      bsD[r] = bih_d[r] + bhh_d[r];
    } else {
      size_t r = idx - S6;
      cv0[r] = be[r];
    }
  }
}

// ---------------- encoder: 32 blocks x 2 batches, serial 128 steps ----------------
__global__ __launch_bounds__(256) void k_enc(
    const float* __restrict__ seq, const int* __restrict__ seq_m,
    const float* __restrict__ Wih, const float* __restrict__ WtE,
    const float* __restrict__ bs,
    float* __restrict__ e, float* __restrict__ hdec, float* __restrict__ cdec) {
  int b0 = blockIdx.x * 2;
  int t = threadIdx.x, c0 = 2 * t;
  __shared__ float hs0[HN], hs1[HN];
  float wih[8], bsr[8];
#pragma unroll
  for (int g = 0; g < 4; ++g) {
    wih[g * 2]     = Wih[g * 512 + c0];
    wih[g * 2 + 1] = Wih[g * 512 + c0 + 1];
    bsr[g * 2]     = bs[g * 512 + c0];
    bsr[g * 2 + 1] = bs[g * 512 + c0 + 1];
  }
  float cr[4] = {0.f, 0.f, 0.f, 0.f};
  hs0[c0] = 0.f; hs0[c0 + 1] = 0.f; hs1[c0] = 0.f; hs1[c0 + 1] = 0.f;
  int len0 = seq_m[b0] - 1, len1 = seq_m[b0 + 1] - 1;
  __syncthreads();
  for (int st = 0; st < LN; ++st) {
    float x0 = seq[b0 * LN + st], x1 = seq[(b0 + 1) * LN + st];
    float a0[8] = {0,0,0,0,0,0,0,0}, a1[8] = {0,0,0,0,0,0,0,0};
#pragma unroll 4
    for (int k = 0; k < HN; ++k) {
      float h0 = hs0[k], h1 = hs1[k];
      const float* wr = WtE + (size_t)k * GN + c0;
      float2 w0 = *(const float2*)(wr);
      float2 w1 = *(const float2*)(wr + 512);
      float2 w2 = *(const float2*)(wr + 1024);
      float2 w3 = *(const float2*)(wr + 1536);
      a0[0] += w0.x * h0; a0[1] += w0.y * h0;
      a0[2] += w1.x * h0; a0[3] += w1.y * h0;
      a0[4] += w2.x * h0; a0[5] += w2.y * h0;
      a0[6] += w3.x * h0; a0[7] += w3.y * h0;
      a1[0] += w0.x * h1; a1[1] += w0.y * h1;
      a1[2] += w1.x * h1; a1[3] += w1.y * h1;
      a1[4] += w2.x * h1; a1[5] += w2.y * h1;
      a1[6] += w3.x * h1; a1[7] += w3.y * h1;
    }
    float hn0[2], hn1[2];
#pragma unroll
    for (int cc = 0; cc < 2; ++cc) {
      float gi = a0[0 + cc] + x0 * wih[0 + cc] + bsr[0 + cc];
      float gf = a0[2 + cc] + x0 * wih[2 + cc] + bsr[2 + cc];
      float gg = a0[4 + cc] + x0 * wih[4 + cc] + bsr[4 + cc];
      float go = a0[6 + cc] + x0 * wih[6 + cc] + bsr[6 + cc];
      float cn = fsig(gf) * cr[cc] + fsig(gi) * ftanh(gg);
      cr[cc] = cn; hn0[cc] = fsig(go) * ftanh(cn);
      gi = a1[0 + cc] + x1 * wih[0 + cc] + bsr[0 + cc];
      gf = a1[2 + cc] + x1 * wih[2 + cc] + bsr[2 + cc];
      gg = a1[4 + cc] + x1 * wih[4 + cc] + bsr[4 + cc];
      go = a1[6 + cc] + x1 * wih[6 + cc] + bsr[6 + cc];
      cn = fsig(gf) * cr[2 + cc] + fsig(gi) * ftanh(gg);
      cr[2 + cc] = cn; hn1[cc] = fsig(go) * ftanh(cn);
    }
    __syncthreads();
    hs0[c0] = hn0[0]; hs0[c0 + 1] = hn0[1];
    hs1[c0] = hn1[0]; hs1[c0 + 1] = hn1[1];
    *(float2*)&e[((size_t)b0 * LN + st) * HN + c0]       = make_float2(hn0[0], hn0[1]);
    *(float2*)&e[((size_t)(b0 + 1) * LN + st) * HN + c0] = make_float2(hn1[0], hn1[1]);
    if (st == len0) {
      hdec[b0 * HN + c0] = hn0[0]; hdec[b0 * HN + c0 + 1] = hn0[1];
      cdec[b0 * HN + c0] = cr[0];  cdec[b0 * HN + c0 + 1] = cr[1];
    }
    if (st == len1) {
      hdec[(b0 + 1) * HN + c0] = hn1[0]; hdec[(b0 + 1) * HN + c0 + 1] = hn1[1];
      cdec[(b0 + 1) * HN + c0] = cr[2];  cdec[(b0 + 1) * HN + c0 + 1] = cr[3];
    }
    __syncthreads();
  }
}

// ---------------- chain: M_i = M_{i-1} @ WeT ; c_i = c_{i-1} @ WeT + be ----------------
__global__ __launch_bounds__(256) void k_chain(
    const float* __restrict__ Msrc, const float* __restrict__ WeT,
    float* __restrict__ Mdst,
    const float* __restrict__ csrc, const float* __restrict__ be,
    float* __restrict__ cdst) {
  int bk = blockIdx.x;  // 128 blocks x 4 rows
  int t = threadIdx.x;
  __shared__ float a[4][HN];
  for (int r = 0; r < 4; ++r)
    for (int k = t; k < HN; k += 256) a[r][k] = Msrc[(size_t)(bk * 4 + r) * HN + k];
  __syncthreads();
  int j0 = t, j1 = t + 256;
  float acc[4][2] = {{0,0},{0,0},{0,0},{0,0}};
#pragma unroll 2
  for (int m = 0; m < HN; ++m) {
    float w0 = WeT[(size_t)m * HN + j0], w1 = WeT[(size_t)m * HN + j1];
#pragma unroll
    for (int r = 0; r < 4; ++r) { acc[r][0] += a[r][m] * w0; acc[r][1] += a[r][m] * w1; }
  }
  for (int r = 0; r < 4; ++r) {
    Mdst[(size_t)(bk * 4 + r) * HN + j0] = acc[r][0];
    Mdst[(size_t)(bk * 4 + r) * HN + j1] = acc[r][1];
  }
  if (bk == 0) {
    float c0a = be[j0], c1a = be[j1];
    for (int m = 0; m < HN; ++m) {
      float cm = csrc[m];
      c0a += cm * WeT[(size_t)m * HN + j0];
      c1a += cm * WeT[(size_t)m * HN + j1];
    }
    cdst[j0] = c0a; cdst[j1] = c1a;
  }
}

// ---------------- big GEMM: ecur[r][j] = sum_k e[r][k]*M[k][j] + cv[j] ----------------
// 64x64 tile, BK=16, 256 threads, 4x4 per thread
__global__ __launch_bounds__(256) void k_big(
    const float* __restrict__ E, const float* __restrict__ M,
    const float* __restrict__ cv, float* __restrict__ out) {
  int tn = blockIdx.x * 64;   // j tile (512/64 = 8)
  int tm = blockIdx.y * 64;   // r tile (8192/64 = 128)
  int t = threadIdx.x;
  __shared__ float As[16][68];  // [k][row]  (pad 68 keeps float4 16B alignment)
  __shared__ float Bs[16][68];  // [k][col]
  int ty = t >> 4, tx = t & 15;
  float acc[4][4] = {{0,0,0,0},{0,0,0,0},{0,0,0,0},{0,0,0,0}};
  int ar = t >> 2, ak = (t & 3) * 4;        // A stage: row ar, k ak..ak+3
  int bk = t >> 4, bj = (t & 15) * 4;       // B stage: k bk, col bj..bj+3
  for (int k0 = 0; k0 < HN; k0 += 16) {
    float4 av = *(const float4*)&E[(size_t)(tm + ar) * HN + k0 + ak];
    float4 bv = *(const float4*)&M[(size_t)(k0 + bk) * HN + tn + bj];
    __syncthreads();
    As[ak + 0][ar] = av.x; As[ak + 1][ar] = av.y; As[ak + 2][ar] = av.z; As[ak + 3][ar] = av.w;
    *(float4*)&Bs[bk][bj] = bv;
    __syncthreads();
#pragma unroll
    for (int kk = 0; kk < 16; ++kk) {
      float4 a4 = *(const float4*)&As[kk][ty * 4];
      float4 b4 = *(const float4*)&Bs[kk][tx * 4];
      acc[0][0] += a4.x * b4.x; acc[0][1] += a4.x * b4.y; acc[0][2] += a4.x * b4.z; acc[0][3] += a4.x * b4.w;
      acc[1][0] += a4.y * b4.x; acc[1][1] += a4.y * b4.y; acc[1][2] += a4.y * b4.z; acc[1][3] += a4.y * b4.w;
      acc[2][0] += a4.z * b4.x; acc[2][1] += a4.z * b4.y; acc[2][2] += a4.z * b4.z; acc[2][3] += a4.z * b4.w;
      acc[3][0] += a4.w * b4.x; acc[3][1] += a4.w * b4.y; acc[3][2] += a4.w * b4.z; acc[3][3] += a4.w * b4.w;
    }
  }
  float4 cvv = *(const float4*)&cv[tn + tx * 4];
#pragma unroll
  for (int i = 0; i < 4; ++i) {
    float4 o;
    o.x = acc[i][0] + cvv.x; o.y = acc[i][1] + cvv.y;
    o.z = acc[i][2] + cvv.z; o.w = acc[i][3] + cvv.w;
    *(float4*)&out[(size_t)(tm + ty * 4 + i) * HN + tn + tx * 4] = o;
  }
}

// ---------------- decoder step: 64 blocks (1 per batch) ----------------
__global__ __launch_bounds__(256) void k_dec(
    int stepi,
    const float* __restrict__ target, const float* __restrict__ seq,
    const float* __restrict__ Wih, const float* __restrict__ WtD,
    const float* __restrict__ bs,  const float* __restrict__ WdT,
    const float* __restrict__ bd,  const float* __restrict__ vv,
    const float* __restrict__ ecur,
    float* __restrict__ hdec, float* __restrict__ cdec,
    float* __restrict__ dbuf, float* __restrict__ out) {
  int b = blockIdx.x, t = threadIdx.x, c0 = 2 * t;
  __shared__ float hs[HN];
  __shared__ float ds[HN];
  __shared__ float ss[LN];
  float x = (stepi == 0) ? target[b * TN + 0]
          : (stepi == 1) ? target[b * TN + 1]
                         : dbuf[b];
  hs[c0] = hdec[b * HN + c0]; hs[c0 + 1] = hdec[b * HN + c0 + 1];
  float cr0 = cdec[b * HN + c0], cr1 = cdec[b * HN + c0 + 1];
  __syncthreads();
  float a[8] = {0,0,0,0,0,0,0,0};
#pragma unroll 4
  for (int k = 0; k < HN; ++k) {
    float hk = hs[k];
    const float* wr = WtD + (size_t)k * GN + c0;
    float2 w0 = *(const float2*)(wr);
    float2 w1 = *(const float2*)(wr + 512);
    float2 w2 = *(const float2*)(wr + 1024);
    float2 w3 = *(const float2*)(wr + 1536);
    a[0] += w0.x * hk; a[1] += w0.y * hk;
    a[2] += w1.x * hk; a[3] += w1.y * hk;
    a[4] += w2.x * hk; a[5] += w2.y * hk;
    a[6] += w3.x * hk; a[7] += w3.y * hk;
  }
  float hn[2], cn[2];
#pragma unroll
  for (int cc = 0; cc < 2; ++cc) {
    int j = c0 + cc;
    float gi = a[0 + cc] + x * Wih[0 * 512 + j] + bs[0 * 512 + j];
    float gf = a[2 + cc] + x * Wih[1 * 512 + j] + bs[1 * 512 + j];
    float gg = a[4 + cc] + x * Wih[2 * 512 + j] + bs[2 * 512 + j];
    float go = a[6 + cc] + x * Wih[3 * 512 + j] + bs[3 * 512 + j];
    float cold = (cc == 0) ? cr0 : cr1;
    float c2 = fsig(gf) * cold + fsig(gi) * ftanh(gg);
    cn[cc] = c2; hn[cc] = fsig(go) * ftanh(c2);
  }
  __syncthreads();
  hs[c0] = hn[0]; hs[c0 + 1] = hn[1];
  hdec[b * HN + c0] = hn[0]; hdec[b * HN + c0 + 1] = hn[1];
  cdec[b * HN + c0] = cn[0]; cdec[b * HN + c0 + 1] = cn[1];
  __syncthreads();
  // d = h_new @ Wd.T + bd
  float d0 = bd[c0], d1 = bd[c0 + 1];
#pragma unroll 4
  for (int k = 0; k < HN; ++k) {
    float hk = hs[k];
    float2 w = *(const float2*)&WdT[(size_t)k * HN + c0];
    d0 += w.x * hk; d1 += w.y * hk;
  }
  ds[c0] = d0; ds[c0 + 1] = d1;
  __syncthreads();
  // scores
  int wave = t >> 6, lane = t & 63;
  for (int l = wave; l < LN; l += 4) {
    const float* er = ecur + ((size_t)b * LN + l) * HN;
    float s = 0.f;
    for (int h = lane; h < HN; h += 64) s += vv[h] * ftanh(er[h] + ds[h]);
#pragma unroll
    for (int off = 32; off >= 1; off >>= 1) s += __shfl_down(s, off);
    if (lane == 0) {
      bool m = (l == 0) || (seq[b * LN + l] != 0.0f);
      ss[l] = m ? s : (s - 1000.0f);
    }
  }
  __syncthreads();
  if (t < 64) {
    float v0 = ss[t], v1 = ss[t + 64];
    float mx; int ix;
    if (v0 >= v1) { mx = v0; ix = t; } else { mx = v1; ix = t + 64; }
#pragma unroll
    for (int off = 32; off >= 1; off >>= 1) {
      float ov = __shfl_down(mx, off);
      int   oi = __shfl_down(ix, off);
      if (ov > mx || (ov == mx && oi < ix)) { mx = ov; ix = oi; }
    }
    mx = __shfl(mx, 0); ix = __shfl(ix, 0);
    float e0 = __expf(v0 - mx), e1 = __expf(v1 - mx);
    float ssum = e0 + e1;
#pragma unroll
    for (int off = 32; off >= 1; off >>= 1) ssum += __shfl_down(ssum, off);
    ssum = __shfl(ssum, 0);
    float inv = 1.0f / ssum;
    out[((size_t)b * TN + stepi) * LN + t]      = e0 * inv;
    out[((size_t)b * TN + stepi) * LN + t + 64] = e1 * inv;
    if (t == 0) {
      float dn = (ix == 0) ? 0.1f : seq[b * LN + ix];
      dbuf[b] = dn;
    }
  }
}

extern "C" void kernel_launch(void* const* d_in, const int* in_sizes, int n_in,
                              void* d_out, int out_size, void* d_ws, size_t ws_size,
                              hipStream_t stream) {
  const float* seq    = (const float*)d_in[0];
  const int*   seq_m  = (const int*)  d_in[1];
  const float* target = (const float*)d_in[2];
  const float* Wih_e  = (const float*)d_in[3];
  const float* Whh_e  = (const float*)d_in[4];
  const float* bih_e  = (const float*)d_in[5];
  const float* bhh_e  = (const float*)d_in[6];
  const float* Wih_d  = (const float*)d_in[7];
  const float* Whh_d  = (const float*)d_in[8];
  const float* bih_d  = (const float*)d_in[9];
  const float* bhh_d  = (const float*)d_in[10];
  const float* We     = (const float*)d_in[11];
  const float* be     = (const float*)d_in[12];
  const float* Wd     = (const float*)d_in[13];
  const float* bd     = (const float*)d_in[14];
  const float* vv     = (const float*)d_in[15];
  float* out = (float*)d_out;
  float* W = (float*)d_ws;

  float* WtE  = W + off_WtE;
  float* WtD  = W + off_WtD;
  float* WeT  = W + off_WeT;
  float* WdT  = W + off_WdT;
  float* Mb[2]  = {W + off_M0, W + off_M1};
  float* cvb[2] = {W + off_cv0, W + off_cv1};
  float* bsE  = W + off_bsE;
  float* bsD  = W + off_bsD;
  float* e    = W + off_e;
  float* ecur = W + off_ecur;
  float* hdec = W + off_hdec;
  float* cdec = W + off_cdec;
  float* dbuf = W + off_dbuf;

  k_prep<<<2048, 256, 0, stream>>>(Whh_e, Whh_d, We, Wd, bih_e, bhh_e, bih_d, bhh_d, be,
                                   WtE, WtD, WeT, Mb[0], WdT, bsE, bsD, cvb[0]);
  k_enc<<<32, 256, 0, stream>>>(seq, seq_m, Wih_e, WtE, bsE, e, hdec, cdec);
  for (int i = 0; i < TN; ++i) {
    if (i > 0) {
      k_chain<<<128, 256, 0, stream>>>(Mb[(i - 1) & 1], WeT, Mb[i & 1],
                                       cvb[(i - 1) & 1], be, cvb[i & 1]);
    }
    dim3 gb(HN / 64, (BN * LN) / 64);
    k_big<<<gb, 256, 0, stream>>>(e, Mb[i & 1], cvb[i & 1], ecur);
    k_dec<<<BN, 256, 0, stream>>>(i, target, seq, Wih_d, WtD, bsD, WdT, bd, vv,
                                  ecur, hdec, cdec, dbuf, out);
  }
}

// Round 2
// 15005.193 us; speedup vs baseline: 1.2194x; 1.2194x over previous
//
#include <hip/hip_runtime.h>
#include <cstddef>
#include <cstdint>

#define BN 64
#define LN 128
#define TN 32
#define HN 512
#define GN 2048  // 4*H

__device__ __forceinline__ float fsig(float x)  { return 1.0f / (1.0f + __expf(-x)); }
__device__ __forceinline__ float ftanh(float x) { return 1.0f - 2.0f / (__expf(2.0f * x) + 1.0f); }

// ---------------- prep: transposes + bias sums + zvec/cnt zero ----------------
__global__ __launch_bounds__(256) void k_prep(
    const float* __restrict__ Whh_e, const float* __restrict__ Whh_d,
    const float* __restrict__ We,    const float* __restrict__ Wd,
    const float* __restrict__ bih_e, const float* __restrict__ bhh_e,
    const float* __restrict__ bih_d, const float* __restrict__ bhh_d,
    const float* __restrict__ be,
    float* __restrict__ WtE, float* __restrict__ WtD,
    float* __restrict__ WdT, float* __restrict__ M0,
    float* __restrict__ bsE, float* __restrict__ bsD,
    float* __restrict__ cva0, float* __restrict__ zvec,
    unsigned int* __restrict__ cnt) {
  const size_t E0 = 1048576, E1 = 2097152, E2 = 2359296, E3 = 2621440,
               E4 = 2623488, E5 = 2625536, E6 = 2626048, E7 = 2626560, E8 = 2626592;
  size_t stride = (size_t)gridDim.x * blockDim.x;
  for (size_t idx = (size_t)blockIdx.x * blockDim.x + threadIdx.x; idx < E8; idx += stride) {
    if (idx < E0) { size_t k = idx >> 11, j = idx & 2047; WtE[idx] = Whh_e[j * 512 + k]; }
    else if (idx < E1) { size_t r = idx - E0, k = r >> 11, j = r & 2047; WtD[r] = Whh_d[j * 512 + k]; }
    else if (idx < E2) { size_t r = idx - E1, k = r >> 9, j = r & 511; WdT[r] = Wd[j * 512 + k]; }
    else if (idx < E3) { size_t r = idx - E2, m = r >> 9, j = r & 511; M0[r] = We[j * 512 + m]; }
    else if (idx < E4) { size_t r = idx - E3; bsE[r] = bih_e[r] + bhh_e[r]; }
    else if (idx < E5) { size_t r = idx - E4; bsD[r] = bih_d[r] + bhh_d[r]; }
    else if (idx < E6) { size_t r = idx - E5; cva0[r] = be[r]; }
    else if (idx < E7) { zvec[idx - E6] = 0.f; }
    else { cnt[idx - E7] = 0u; }
  }
}

// ---------------- encoder: 128 persistent blocks, c-split x4 per batch-pair ----------------
// block = group g (batches 2g,2g+1) x quarter q (c in [q*128,(q+1)*128))
// per step each block streams only 1MB of WtE (k-major, coalesced on c).
__global__ __launch_bounds__(256) void k_enc2(
    const float* __restrict__ seq, const int* __restrict__ seq_m,
    const float* __restrict__ Wih, const float* __restrict__ WtE,
    const float* __restrict__ bs,
    float* __restrict__ e, float* __restrict__ hdec, float* __restrict__ cdec,
    float* __restrict__ hx /*[2][64][512]*/, unsigned int* __restrict__ cnt /*[32]*/) {
  int blk = blockIdx.x;
  int g = blk >> 2, q = blk & 3;
  int b0 = g * 2;
  int c0 = q * 128;
  int t = threadIdx.x;
  int c_idx = t & 127, kh = t >> 7;   // compute role: k-half kh, column c
  int c = c0 + c_idx;
  __shared__ float hs[2][HN];
  __shared__ float P[2][2][128][4];   // [kh][b][c_idx][gate]
  for (int i = t; i < 2 * HN; i += 256) ((float*)hs)[i] = 0.f;
  float wih_r[4], bs_r[4];
#pragma unroll
  for (int gg2 = 0; gg2 < 4; ++gg2) { wih_r[gg2] = Wih[gg2 * 512 + c]; bs_r[gg2] = bs[gg2 * 512 + c]; }
  float cstate = 0.f;
  int bsel = kh;                       // epilogue role: batch bsel, column c
  int len = seq_m[b0 + bsel] - 1;
  unsigned int* cg = cnt + g;
  __syncthreads();
  for (int st = 0; st < LN; ++st) {
    if (st > 0) {
      const float* src = hx + (size_t)((st & 1) ^ 1) * (BN * HN);
      for (int i = t; i < 2 * HN; i += 256) {
        int bb = i >> 9, kk = i & 511;
        hs[bb][kk] = __hip_atomic_load(src + (size_t)(b0 + bb) * HN + kk,
                                       __ATOMIC_RELAXED, __HIP_MEMORY_SCOPE_AGENT);
      }
      __syncthreads();
    }
    // compute role: partial gates over k-half
    float a00 = 0, a01 = 0, a10 = 0, a11 = 0, a20 = 0, a21 = 0, a30 = 0, a31 = 0;
    const float* wbase = WtE + (size_t)(kh * 256) * GN + c;
    const float* h0p = &hs[0][kh * 256];
    const float* h1p = &hs[1][kh * 256];
#pragma unroll 4
    for (int kk = 0; kk < 256; ++kk) {
      float h0 = h0p[kk], h1 = h1p[kk];
      const float* wr = wbase + (size_t)kk * GN;
      float w0 = wr[0], w1 = wr[512], w2 = wr[1024], w3 = wr[1536];
      a00 += w0 * h0; a01 += w0 * h1;
      a10 += w1 * h0; a11 += w1 * h1;
      a20 += w2 * h0; a21 += w2 * h1;
      a30 += w3 * h0; a31 += w3 * h1;
    }
    P[kh][0][c_idx][0] = a00; P[kh][0][c_idx][1] = a10; P[kh][0][c_idx][2] = a20; P[kh][0][c_idx][3] = a30;
    P[kh][1][c_idx][0] = a01; P[kh][1][c_idx][1] = a11; P[kh][1][c_idx][2] = a21; P[kh][1][c_idx][3] = a31;
    __syncthreads();
    // epilogue role: (c, bsel)
    float x = seq[(b0 + bsel) * LN + st];
    float gi = P[0][bsel][c_idx][0] + P[1][bsel][c_idx][0] + x * wih_r[0] + bs_r[0];
    float gf = P[0][bsel][c_idx][1] + P[1][bsel][c_idx][1] + x * wih_r[1] + bs_r[1];
    float gg = P[0][bsel][c_idx][2] + P[1][bsel][c_idx][2] + x * wih_r[2] + bs_r[2];
    float go = P[0][bsel][c_idx][3] + P[1][bsel][c_idx][3] + x * wih_r[3] + bs_r[3];
    float cn = fsig(gf) * cstate + fsig(gi) * ftanh(gg);
    cstate = cn;
    float hn = fsig(go) * ftanh(cn);
    e[((size_t)(b0 + bsel) * LN + st) * HN + c] = hn;
    hx[(size_t)(st & 1) * (BN * HN) + (size_t)(b0 + bsel) * HN + c] = hn;
    if (st == len) { hdec[(b0 + bsel) * HN + c] = hn; cdec[(b0 + bsel) * HN + c] = cn; }
    __syncthreads();   // per-thread stores drained (vmcnt) before t0's fence
    if (t == 0) {
      __threadfence();                 // agent fence: L2 writeback
      atomicAdd(cg, 1u);               // device-scope
      unsigned int tgt = 4u * (unsigned)(st + 1);
      while (__hip_atomic_load(cg, __ATOMIC_ACQUIRE, __HIP_MEMORY_SCOPE_AGENT) < tgt)
        __builtin_amdgcn_s_sleep(2);
    }
    __syncthreads();
  }
}

// ---------------- generic GEMM: O[z] = A[z](Mx512) @ B[z](512x512) + CV[z], z-batched ----------------
// 128x128 tile, BK=8, 256 threads, 8x8 per thread
__global__ __launch_bounds__(256) void k_gemm(
    const float* __restrict__ Ab, const float* __restrict__ Bb,
    const float* __restrict__ Cvb, float* __restrict__ Ob,
    size_t Asz, size_t Bsz, size_t Cvsz, size_t Osz) {
  int z = blockIdx.z;
  const float* A = Ab + (size_t)z * Asz;
  const float* B = Bb + (size_t)z * Bsz;
  const float* CV = Cvb + (size_t)z * Cvsz;
  float* O = Ob + (size_t)z * Osz;
  int tn = blockIdx.x * 128;
  int tm = blockIdx.y * 128;
  int t = threadIdx.x;
  __shared__ float As[8][132];
  __shared__ float Bs[8][132];
  int ar = t >> 1, ak4 = (t & 1) * 4;
  int bk2 = t >> 5, bj = (t & 31) * 4;
  int ty = t >> 4, tx = t & 15;
  float acc[8][8];
#pragma unroll
  for (int i = 0; i < 8; ++i)
#pragma unroll
    for (int j = 0; j < 8; ++j) acc[i][j] = 0.f;
  for (int k0 = 0; k0 < 512; k0 += 8) {
    float4 av = *(const float4*)&A[(size_t)(tm + ar) * 512 + k0 + ak4];
    float4 bv = *(const float4*)&B[(size_t)(k0 + bk2) * 512 + tn + bj];
    __syncthreads();
    As[ak4 + 0][ar] = av.x; As[ak4 + 1][ar] = av.y; As[ak4 + 2][ar] = av.z; As[ak4 + 3][ar] = av.w;
    *(float4*)&Bs[bk2][bj] = bv;
    __syncthreads();
#pragma unroll
    for (int kk = 0; kk < 8; ++kk) {
      float4 A0 = *(const float4*)&As[kk][ty * 8];
      float4 A1 = *(const float4*)&As[kk][ty * 8 + 4];
      float4 B0 = *(const float4*)&Bs[kk][tx * 8];
      float4 B1 = *(const float4*)&Bs[kk][tx * 8 + 4];
      float am[8] = {A0.x, A0.y, A0.z, A0.w, A1.x, A1.y, A1.z, A1.w};
      float bn[8] = {B0.x, B0.y, B0.z, B0.w, B1.x, B1.y, B1.z, B1.w};
#pragma unroll
      for (int i2 = 0; i2 < 8; ++i2)
#pragma unroll
        for (int j2 = 0; j2 < 8; ++j2) acc[i2][j2] += am[i2] * bn[j2];
    }
  }
  float4 cv0 = *(const float4*)&CV[tn + tx * 8];
  float4 cv1 = *(const float4*)&CV[tn + tx * 8 + 4];
  float cvv[8] = {cv0.x, cv0.y, cv0.z, cv0.w, cv1.x, cv1.y, cv1.z, cv1.w};
#pragma unroll
  for (int r = 0; r < 8; ++r) {
    float4 o0, o1;
    o0.x = acc[r][0] + cvv[0]; o0.y = acc[r][1] + cvv[1]; o0.z = acc[r][2] + cvv[2]; o0.w = acc[r][3] + cvv[3];
    o1.x = acc[r][4] + cvv[4]; o1.y = acc[r][5] + cvv[5]; o1.z = acc[r][6] + cvv[6]; o1.w = acc[r][7] + cvv[7];
    *(float4*)&O[(size_t)(tm + ty * 8 + r) * 512 + tn + tx * 8]     = o0;
    *(float4*)&O[(size_t)(tm + ty * 8 + r) * 512 + tn + tx * 8 + 4] = o1;
  }
}

// ---------------- vtmp[k] = be @ M_k (mega) ----------------
__global__ __launch_bounds__(256) void k_cvec(
    const float* __restrict__ be, const float* __restrict__ Mall, float* __restrict__ vtmp) {
  int k = blockIdx.x, t = threadIdx.x;
  const float* M = Mall + (size_t)k * 262144;
  float a0 = 0.f, a1 = 0.f;
  for (int m = 0; m < 512; ++m) {
    float bm = be[m];
    a0 += bm * M[(size_t)m * 512 + t];
    a1 += bm * M[(size_t)m * 512 + t + 256];
  }
  vtmp[(size_t)k * 512 + t] = a0;
  vtmp[(size_t)k * 512 + t + 256] = a1;
}

// ---------------- cva[i] = be + sum_{k<i} vtmp[k] (mega) ----------------
__global__ __launch_bounds__(512) void k_cpref(
    const float* __restrict__ be, const float* __restrict__ vtmp, float* __restrict__ cva) {
  int j = threadIdx.x;
  float run = be[j];
  for (int i = 0; i < 32; ++i) {
    cva[(size_t)i * 512 + j] = run;
    if (i < 31) run += vtmp[(size_t)i * 512 + j];
  }
}

// ---------------- cdst = csrc @ M0 + be (fallback) ----------------
__global__ __launch_bounds__(512) void k_cstep(
    const float* __restrict__ csrc, const float* __restrict__ M0,
    const float* __restrict__ be, float* __restrict__ cdst) {
  int j = threadIdx.x;
  float a = be[j];
  for (int m = 0; m < 512; ++m) a += csrc[m] * M0[(size_t)m * 512 + j];
  cdst[j] = a;
}

// ---------------- decoder step: 64 blocks (1 per batch) ----------------
__global__ __launch_bounds__(256) void k_dec(
    int stepi,
    const float* __restrict__ target, const float* __restrict__ seq,
    const float* __restrict__ Wih, const float* __restrict__ WtD,
    const float* __restrict__ bs,  const float* __restrict__ WdT,
    const float* __restrict__ bd,  const float* __restrict__ vv,
    const float* __restrict__ ecur,
    float* __restrict__ hdec, float* __restrict__ cdec,
    float* __restrict__ dbuf, float* __restrict__ out) {
  int b = blockIdx.x, t = threadIdx.x, c0 = 2 * t;
  __shared__ float hs[HN];
  __shared__ float ds[HN];
  __shared__ float ss[LN];
  float x = (stepi == 0) ? target[b * TN + 0]
          : (stepi == 1) ? target[b * TN + 1]
                         : dbuf[b];
  hs[c0] = hdec[b * HN + c0]; hs[c0 + 1] = hdec[b * HN + c0 + 1];
  float cr0 = cdec[b * HN + c0], cr1 = cdec[b * HN + c0 + 1];
  __syncthreads();
  float a[8] = {0, 0, 0, 0, 0, 0, 0, 0};
#pragma unroll 4
  for (int k = 0; k < HN; ++k) {
    float hk = hs[k];
    const float* wr = WtD + (size_t)k * GN + c0;
    float2 w0 = *(const float2*)(wr);
    float2 w1 = *(const float2*)(wr + 512);
    float2 w2 = *(const float2*)(wr + 1024);
    float2 w3 = *(const float2*)(wr + 1536);
    a[0] += w0.x * hk; a[1] += w0.y * hk;
    a[2] += w1.x * hk; a[3] += w1.y * hk;
    a[4] += w2.x * hk; a[5] += w2.y * hk;
    a[6] += w3.x * hk; a[7] += w3.y * hk;
  }
  float hn[2], cn[2];
#pragma unroll
  for (int cc = 0; cc < 2; ++cc) {
    int j = c0 + cc;
    float gi = a[0 + cc] + x * Wih[0 * 512 + j] + bs[0 * 512 + j];
    float gf = a[2 + cc] + x * Wih[1 * 512 + j] + bs[1 * 512 + j];
    float gg = a[4 + cc] + x * Wih[2 * 512 + j] + bs[2 * 512 + j];
    float go = a[6 + cc] + x * Wih[3 * 512 + j] + bs[3 * 512 + j];
    float cold = (cc == 0) ? cr0 : cr1;
    float c2 = fsig(gf) * cold + fsig(gi) * ftanh(gg);
    cn[cc] = c2; hn[cc] = fsig(go) * ftanh(c2);
  }
  __syncthreads();
  hs[c0] = hn[0]; hs[c0 + 1] = hn[1];
  hdec[b * HN + c0] = hn[0]; hdec[b * HN + c0 + 1] = hn[1];
  cdec[b * HN + c0] = cn[0]; cdec[b * HN + c0 + 1] = cn[1];
  __syncthreads();
  float d0 = bd[c0], d1 = bd[c0 + 1];
#pragma unroll 4
  for (int k = 0; k < HN; ++k) {
    float hk = hs[k];
    float2 w = *(const float2*)&WdT[(size_t)k * HN + c0];
    d0 += w.x * hk; d1 += w.y * hk;
  }
  ds[c0] = d0; ds[c0 + 1] = d1;
  __syncthreads();
  int wave = t >> 6, lane = t & 63;
  for (int l = wave; l < LN; l += 4) {
    const float* er = ecur + ((size_t)b * LN + l) * HN;
    float s = 0.f;
    for (int h = lane; h < HN; h += 64) s += vv[h] * ftanh(er[h] + ds[h]);
#pragma unroll
    for (int off = 32; off >= 1; off >>= 1) s += __shfl_down(s, off);
    if (lane == 0) {
      bool m = (l == 0) || (seq[b * LN + l] != 0.0f);
      ss[l] = m ? s : (s - 1000.0f);
    }
  }
  __syncthreads();
  if (t < 64) {
    float v0 = ss[t], v1 = ss[t + 64];
    float mx; int ix;
    if (v0 >= v1) { mx = v0; ix = t; } else { mx = v1; ix = t + 64; }
#pragma unroll
    for (int off = 32; off >= 1; off >>= 1) {
      float ov = __shfl_down(mx, off);
      int   oi = __shfl_down(ix, off);
      if (ov > mx || (ov == mx && oi < ix)) { mx = ov; ix = oi; }
    }
    mx = __shfl(mx, 0); ix = __shfl(ix, 0);
    float e0 = __expf(v0 - mx), e1 = __expf(v1 - mx);
    float ssum = e0 + e1;
#pragma unroll
    for (int off = 32; off >= 1; off >>= 1) ssum += __shfl_down(ssum, off);
    ssum = __shfl(ssum, 0);
    float inv = 1.0f / ssum;
    out[((size_t)b * TN + stepi) * LN + t]      = e0 * inv;
    out[((size_t)b * TN + stepi) * LN + t + 64] = e1 * inv;
    if (t == 0) {
      float dn = (ix == 0) ? 0.1f : seq[b * LN + ix];
      dbuf[b] = dn;
    }
  }
}

extern "C" void kernel_launch(void* const* d_in, const int* in_sizes, int n_in,
                              void* d_out, int out_size, void* d_ws, size_t ws_size,
                              hipStream_t stream) {
  const float* seq    = (const float*)d_in[0];
  const int*   seq_m  = (const int*)  d_in[1];
  const float* target = (const float*)d_in[2];
  const float* Wih_e  = (const float*)d_in[3];
  const float* Whh_e  = (const float*)d_in[4];
  const float* bih_e  = (const float*)d_in[5];
  const float* bhh_e  = (const float*)d_in[6];
  const float* Wih_d  = (const float*)d_in[7];
  const float* Whh_d  = (const float*)d_in[8];
  const float* bih_d  = (const float*)d_in[9];
  const float* bhh_d  = (const float*)d_in[10];
  const float* We     = (const float*)d_in[11];
  const float* be     = (const float*)d_in[12];
  const float* Wd     = (const float*)d_in[13];
  const float* bd     = (const float*)d_in[14];
  const float* vv     = (const float*)d_in[15];
  float* out = (float*)d_out;
  float* W = (float*)d_ws;

  const size_t MEGA_FLOATS = 149327968ull;         // ~597 MB
  bool mega = ws_size >= MEGA_FLOATS * sizeof(float);
  size_t nM = mega ? 32 : 3, nCv = mega ? 32 : 2, nEc = mega ? 32 : 1;

  size_t o = 0;
  float* WtE = W + o; o += 1048576;
  float* WtD = W + o; o += 1048576;
  float* WdT = W + o; o += 262144;
  float* Mall = W + o; o += nM * 262144;
  float* vtmp = W + o; o += mega ? 15872 : 0;
  float* cva = W + o; o += nCv * 512;
  float* bsE = W + o; o += 2048;
  float* bsD = W + o; o += 2048;
  float* zvec = W + o; o += 512;
  unsigned int* cnt = (unsigned int*)(W + o); o += 32;
  float* hx = W + o; o += 65536;
  float* hdec = W + o; o += 32768;
  float* cdec = W + o; o += 32768;
  float* dbuf = W + o; o += 64;
  float* e = W + o; o += 4194304;
  float* ecur = W + o; o += nEc * 4194304;

  k_prep<<<2048, 256, 0, stream>>>(Whh_e, Whh_d, We, Wd, bih_e, bhh_e, bih_d, bhh_d, be,
                                   WtE, WtD, WdT, Mall, bsE, bsD, cva, zvec, cnt);
  k_enc2<<<128, 256, 0, stream>>>(seq, seq_m, Wih_e, WtE, bsE, e, hdec, cdec, hx, cnt);

  if (mega) {
    // log-doubling: M_{p+z} = M_z @ M_{p-1}
    for (int r = 0; r < 5; ++r) {
      int p = 1 << r;
      dim3 gp(4, 4, p);
      k_gemm<<<gp, 256, 0, stream>>>(Mall, Mall + (size_t)(p - 1) * 262144, zvec,
                                     Mall + (size_t)p * 262144,
                                     262144, 0, 0, 262144);
    }
    k_cvec<<<31, 256, 0, stream>>>(be, Mall, vtmp);
    k_cpref<<<1, 512, 0, stream>>>(be, vtmp, cva);
    dim3 gb(4, 64, 32);
    k_gemm<<<gb, 256, 0, stream>>>(e, Mall, cva, ecur, 0, 262144, 512, 4194304);
    for (int i = 0; i < TN; ++i)
      k_dec<<<BN, 256, 0, stream>>>(i, target, seq, Wih_d, WtD, bsD, WdT, bd, vv,
                                    ecur + (size_t)i * 4194304, hdec, cdec, dbuf, out);
  } else {
    for (int i = 0; i < TN; ++i) {
      const float* Mi; const float* ci;
      if (i == 0) { Mi = Mall; ci = cva; }
      else {
        float* Msrc = (i == 1) ? Mall : Mall + (size_t)(1 + (i & 1)) * 262144;
        float* Mdst = Mall + (size_t)(1 + ((i - 1) & 1)) * 262144;
        dim3 gp(4, 4, 1);
        k_gemm<<<gp, 256, 0, stream>>>(Msrc, Mall, zvec, Mdst, 0, 0, 0, 0);
        k_cstep<<<1, 512, 0, stream>>>(cva + (size_t)((i - 1) & 1) * 512, Mall, be,
                                       cva + (size_t)(i & 1) * 512);
        Mi = Mdst; ci = cva + (size_t)(i & 1) * 512;
      }
      dim3 gb(4, 64, 1);
      k_gemm<<<gb, 256, 0, stream>>>(e, Mi, ci, ecur, 0, 0, 0, 0);
      k_dec<<<BN, 256, 0, stream>>>(i, target, seq, Wih_d, WtD, bsD, WdT, bd, vv,
                                    ecur, hdec, cdec, dbuf, out);
    }
  }
}

// Round 3
// 6234.438 us; speedup vs baseline: 2.9348x; 2.4068x over previous
//
#include <hip/hip_runtime.h>
#include <cstddef>
#include <cstdint>

#define BN 64
#define LN 128
#define TN 32
#define HN 512
#define GN 2048

__device__ __forceinline__ float fsig(float x)  { return 1.0f / (1.0f + __expf(-x)); }
__device__ __forceinline__ float ftanh(float x) { return 1.0f - 2.0f / (__expf(2.0f * x) + 1.0f); }

// ---------- gate-packed transpose: Wt4[k][c][g] = Whh[g*512+c][k] ----------
__global__ __launch_bounds__(256) void k_tpack(
    const float* __restrict__ Whh_e, const float* __restrict__ Whh_d,
    float* __restrict__ Wt4E, float* __restrict__ Wt4D) {
  int blk = blockIdx.x;
  const float* src = (blk >> 7) ? Whh_d : Whh_e;
  float* dst = (blk >> 7) ? Wt4D : Wt4E;
  int r = blk & 127;
  int kt = r >> 4, ct = r & 15;     // k-tile of 64, c-tile of 32
  int t = threadIdx.x;
  __shared__ float L[4][32][65];
  int cl = t >> 3, k8 = (t & 7) * 8;
#pragma unroll
  for (int g = 0; g < 4; ++g) {
    float4 a = *(const float4*)&src[(size_t)(g * 512 + ct * 32 + cl) * 512 + kt * 64 + k8];
    float4 b = *(const float4*)&src[(size_t)(g * 512 + ct * 32 + cl) * 512 + kt * 64 + k8 + 4];
    L[g][cl][k8 + 0] = a.x; L[g][cl][k8 + 1] = a.y; L[g][cl][k8 + 2] = a.z; L[g][cl][k8 + 3] = a.w;
    L[g][cl][k8 + 4] = b.x; L[g][cl][k8 + 5] = b.y; L[g][cl][k8 + 6] = b.z; L[g][cl][k8 + 7] = b.w;
  }
  __syncthreads();
  int kl = t >> 2, c8 = (t & 3) * 8;
#pragma unroll
  for (int i = 0; i < 8; ++i) {
    int c = c8 + i;
    float4 v = make_float4(L[0][c][kl], L[1][c][kl], L[2][c][kl], L[3][c][kl]);
    *(float4*)&dst[((size_t)(kt * 64 + kl) * 512 + ct * 32 + c) * 4] = v;
  }
}

// ---------- plain 512x512 transpose: dst[m][j] = src[j][m] ----------
__global__ __launch_bounds__(256) void k_tr(
    const float* __restrict__ We, const float* __restrict__ Wd,
    float* __restrict__ M0, float* __restrict__ WdT) {
  int blk = blockIdx.x;
  const float* src = (blk >> 8) ? Wd : We;
  float* dst = (blk >> 8) ? WdT : M0;
  int r = blk & 255;
  int rt = r >> 4, ct = r & 15;
  int t = threadIdx.x;
  __shared__ float T[32][33];
  int jl = t >> 3, m4 = (t & 7) * 4;
  float4 a = *(const float4*)&src[(size_t)(ct * 32 + jl) * 512 + rt * 32 + m4];
  T[jl][m4 + 0] = a.x; T[jl][m4 + 1] = a.y; T[jl][m4 + 2] = a.z; T[jl][m4 + 3] = a.w;
  __syncthreads();
  int ml = t >> 3, j4 = (t & 7) * 4;
  float4 v = make_float4(T[j4 + 0][ml], T[j4 + 1][ml], T[j4 + 2][ml], T[j4 + 3][ml]);
  *(float4*)&dst[(size_t)(rt * 32 + ml) * 512 + ct * 32 + j4] = v;
}

// ---------- small packs: Wih4, bs4, zvec, cnt, cva0 ----------
__global__ __launch_bounds__(256) void k_small(
    const float* __restrict__ Wih_e, const float* __restrict__ Wih_d,
    const float* __restrict__ bih_e, const float* __restrict__ bhh_e,
    const float* __restrict__ bih_d, const float* __restrict__ bhh_d,
    const float* __restrict__ be,
    float* __restrict__ WihE4, float* __restrict__ WihD4,
    float* __restrict__ bsE4, float* __restrict__ bsD4,
    float* __restrict__ zvec, unsigned int* __restrict__ cnt,
    float* __restrict__ cva0) {
  int idx = blockIdx.x * 256 + threadIdx.x;
  if (idx < 2048) { int c = idx >> 2, g = idx & 3; WihE4[idx] = Wih_e[g * 512 + c]; }
  else if (idx < 4096) { int r = idx - 2048; int c = r >> 2, g = r & 3; WihD4[r] = Wih_d[g * 512 + c]; }
  else if (idx < 6144) { int r = idx - 4096; int c = r >> 2, g = r & 3; bsE4[r] = bih_e[g * 512 + c] + bhh_e[g * 512 + c]; }
  else if (idx < 8192) { int r = idx - 6144; int c = r >> 2, g = r & 3; bsD4[r] = bih_d[g * 512 + c] + bhh_d[g * 512 + c]; }
  else if (idx < 8704) { zvec[idx - 8192] = 0.f; }
  else if (idx < 8736) { cnt[idx - 8704] = 0u; }
  else if (idx < 9248) { cva0[idx - 8736] = be[idx - 8736]; }
}

// ---------- encoder: 256 persistent blocks (16 groups x 4 batches x 16 c-slices) ----------
__global__ __launch_bounds__(512) void k_enc(
    const float* __restrict__ seq, const int* __restrict__ seq_m,
    const float* __restrict__ WihE4, const float* __restrict__ Wt4E,
    const float* __restrict__ bsE4,
    float* __restrict__ e, float* __restrict__ hdec, float* __restrict__ cdec,
    float* __restrict__ hx, unsigned int* __restrict__ cnt) {
  int blk = blockIdx.x;
  int g = blk & 15, s = blk >> 4;
  int b0 = g * 4;
  int t = threadIdx.x;
  int c_idx = t & 31, kq = t >> 5;            // kq in [0,16), 32 k each
  int c = s * 32 + c_idx;
  __shared__ float hs[4][HN];
  __shared__ float P[16][4][32][4];
  for (int i = t; i < 4 * HN; i += 512) ((float*)hs)[i] = 0.f;
  // epilogue-role registers (threads t<128): bb = t>>5, ci = t&31
  int ebb = t >> 5, eci = t & 31;
  float cstate = 0.f;
  float4 wih = make_float4(0, 0, 0, 0), bs4 = make_float4(0, 0, 0, 0);
  int len = -2;
  if (t < 128) {
    int ec = s * 32 + eci;
    wih = *(const float4*)&WihE4[ec * 4];
    bs4 = *(const float4*)&bsE4[ec * 4];
    len = seq_m[b0 + ebb] - 1;
  }
  unsigned int* cg = cnt + g;
  const float* wbase = Wt4E + ((size_t)(kq * 32) * 512 + c) * 4;
  __syncthreads();
  for (int st = 0; st < LN; ++st) {
    if (st > 0) {
      const float* src = hx + (size_t)((st & 1) ^ 1) * (BN * HN);
      for (int i = t; i < 4 * HN; i += 512) {
        int bb = i >> 9, kk = i & 511;
        hs[bb][kk] = __hip_atomic_load(src + (size_t)(b0 + bb) * HN + kk,
                                       __ATOMIC_RELAXED, __HIP_MEMORY_SCOPE_AGENT);
      }
      __syncthreads();
    }
    float4 acc0 = make_float4(0, 0, 0, 0), acc1 = acc0, acc2 = acc0, acc3 = acc0;
#pragma unroll
    for (int kk4 = 0; kk4 < 8; ++kk4) {
      float4 h0 = *(const float4*)&hs[0][kq * 32 + kk4 * 4];
      float4 h1 = *(const float4*)&hs[1][kq * 32 + kk4 * 4];
      float4 h2 = *(const float4*)&hs[2][kq * 32 + kk4 * 4];
      float4 h3 = *(const float4*)&hs[3][kq * 32 + kk4 * 4];
      const float* wp = wbase + (size_t)(kk4 * 4) * 2048;
#pragma unroll
      for (int u = 0; u < 4; ++u) {
        float4 w = *(const float4*)(wp + (size_t)u * 2048);
        float hu0 = (&h0.x)[u], hu1 = (&h1.x)[u], hu2 = (&h2.x)[u], hu3 = (&h3.x)[u];
        acc0.x += w.x * hu0; acc0.y += w.y * hu0; acc0.z += w.z * hu0; acc0.w += w.w * hu0;
        acc1.x += w.x * hu1; acc1.y += w.y * hu1; acc1.z += w.z * hu1; acc1.w += w.w * hu1;
        acc2.x += w.x * hu2; acc2.y += w.y * hu2; acc2.z += w.z * hu2; acc2.w += w.w * hu2;
        acc3.x += w.x * hu3; acc3.y += w.y * hu3; acc3.z += w.z * hu3; acc3.w += w.w * hu3;
      }
    }
    *(float4*)&P[kq][0][c_idx][0] = acc0;
    *(float4*)&P[kq][1][c_idx][0] = acc1;
    *(float4*)&P[kq][2][c_idx][0] = acc2;
    *(float4*)&P[kq][3][c_idx][0] = acc3;
    __syncthreads();
    if (t < 128) {
      int b = b0 + ebb, ec = s * 32 + eci;
      float4 gsum = make_float4(0, 0, 0, 0);
#pragma unroll
      for (int q = 0; q < 16; ++q) {
        float4 p = *(const float4*)&P[q][ebb][eci][0];
        gsum.x += p.x; gsum.y += p.y; gsum.z += p.z; gsum.w += p.w;
      }
      float x = seq[b * LN + st];
      float gi = gsum.x + x * wih.x + bs4.x;
      float gf = gsum.y + x * wih.y + bs4.y;
      float gg = gsum.z + x * wih.z + bs4.z;
      float go = gsum.w + x * wih.w + bs4.w;
      float cn = fsig(gf) * cstate + fsig(gi) * ftanh(gg);
      cstate = cn;
      float hn = fsig(go) * ftanh(cn);
      e[((size_t)b * LN + st) * HN + ec] = hn;
      hx[(size_t)(st & 1) * (BN * HN) + (size_t)b * HN + ec] = hn;
      if (st == len) { hdec[(size_t)b * HN + ec] = hn; cdec[(size_t)b * HN + ec] = cn; }
    }
    __syncthreads();
    if (t == 0) {
      __threadfence();
      atomicAdd(cg, 1u);
      unsigned int tgt = 16u * (unsigned)(st + 1);
      while (__hip_atomic_load(cg, __ATOMIC_ACQUIRE, __HIP_MEMORY_SCOPE_AGENT) < tgt)
        __builtin_amdgcn_s_sleep(2);
    }
    __syncthreads();
  }
}

// ---------- generic 512-K GEMM (used for M-power doubling) ----------
__global__ __launch_bounds__(256) void k_gemm(
    const float* __restrict__ Ab, const float* __restrict__ Bb,
    const float* __restrict__ Cvb, float* __restrict__ Ob,
    size_t Asz, size_t Bsz, size_t Cvsz, size_t Osz) {
  int z = blockIdx.z;
  const float* A = Ab + (size_t)z * Asz;
  const float* B = Bb + (size_t)z * Bsz;
  const float* CV = Cvb + (size_t)z * Cvsz;
  float* O = Ob + (size_t)z * Osz;
  int tn = blockIdx.x * 128;
  int tm = blockIdx.y * 128;
  int t = threadIdx.x;
  __shared__ float As[8][132];
  __shared__ float Bs[8][132];
  int ar = t >> 1, ak4 = (t & 1) * 4;
  int bk2 = t >> 5, bj = (t & 31) * 4;
  int ty = t >> 4, tx = t & 15;
  float acc[8][8];
#pragma unroll
  for (int i = 0; i < 8; ++i)
#pragma unroll
    for (int j = 0; j < 8; ++j) acc[i][j] = 0.f;
  for (int k0 = 0; k0 < 512; k0 += 8) {
    float4 av = *(const float4*)&A[(size_t)(tm + ar) * 512 + k0 + ak4];
    float4 bv = *(const float4*)&B[(size_t)(k0 + bk2) * 512 + tn + bj];
    __syncthreads();
    As[ak4 + 0][ar] = av.x; As[ak4 + 1][ar] = av.y; As[ak4 + 2][ar] = av.z; As[ak4 + 3][ar] = av.w;
    *(float4*)&Bs[bk2][bj] = bv;
    __syncthreads();
#pragma unroll
    for (int kk = 0; kk < 8; ++kk) {
      float4 A0 = *(const float4*)&As[kk][ty * 8];
      float4 A1 = *(const float4*)&As[kk][ty * 8 + 4];
      float4 B0 = *(const float4*)&Bs[kk][tx * 8];
      float4 B1 = *(const float4*)&Bs[kk][tx * 8 + 4];
      float am[8] = {A0.x, A0.y, A0.z, A0.w, A1.x, A1.y, A1.z, A1.w};
      float bn[8] = {B0.x, B0.y, B0.z, B0.w, B1.x, B1.y, B1.z, B1.w};
#pragma unroll
      for (int i2 = 0; i2 < 8; ++i2)
#pragma unroll
        for (int j2 = 0; j2 < 8; ++j2) acc[i2][j2] += am[i2] * bn[j2];
    }
  }
  float4 cv0 = *(const float4*)&CV[tn + tx * 8];
  float4 cv1 = *(const float4*)&CV[tn + tx * 8 + 4];
  float cvv[8] = {cv0.x, cv0.y, cv0.z, cv0.w, cv1.x, cv1.y, cv1.z, cv1.w};
#pragma unroll
  for (int r = 0; r < 8; ++r) {
    float4 o0, o1;
    o0.x = acc[r][0] + cvv[0]; o0.y = acc[r][1] + cvv[1]; o0.z = acc[r][2] + cvv[2]; o0.w = acc[r][3] + cvv[3];
    o1.x = acc[r][4] + cvv[4]; o1.y = acc[r][5] + cvv[5]; o1.z = acc[r][6] + cvv[6]; o1.w = acc[r][7] + cvv[7];
    *(float4*)&O[(size_t)(tm + ty * 8 + r) * 512 + tn + tx * 8]     = o0;
    *(float4*)&O[(size_t)(tm + ty * 8 + r) * 512 + tn + tx * 8 + 4] = o1;
  }
}

// ---------- vtmp[k] = be @ M_k ----------
__global__ __launch_bounds__(256) void k_cvec(
    const float* __restrict__ be, const float* __restrict__ Mall, float* __restrict__ vtmp) {
  int k = blockIdx.x, t = threadIdx.x;
  const float* M = Mall + (size_t)k * 262144;
  float a0 = 0.f, a1 = 0.f;
  for (int m = 0; m < 512; ++m) {
    float bm = be[m];
    a0 += bm * M[(size_t)m * 512 + t];
    a1 += bm * M[(size_t)m * 512 + t + 256];
  }
  vtmp[(size_t)k * 512 + t] = a0;
  vtmp[(size_t)k * 512 + t + 256] = a1;
}

__global__ __launch_bounds__(512) void k_cpref(
    const float* __restrict__ be, const float* __restrict__ vtmp, float* __restrict__ cva) {
  int j = threadIdx.x;
  float run = be[j];
  for (int i = 0; i < 32; ++i) {
    cva[(size_t)i * 512 + j] = run;
    if (i < 31) run += vtmp[(size_t)i * 512 + j];
  }
}

__global__ __launch_bounds__(512) void k_cstep(
    const float* __restrict__ csrc, const float* __restrict__ M0,
    const float* __restrict__ be, float* __restrict__ cdst) {
  int j = threadIdx.x;
  float a = be[j];
  for (int m = 0; m < 512; ++m) a += csrc[m] * M0[(size_t)m * 512 + j];
  cdst[j] = a;
}

// ---------- decoder LSTM step (+ prev-step softmax/argmax/out) ----------
// grid 256: bq in [0,16) x s in [0,16); 4 batches x 32 j's
__global__ __launch_bounds__(256) void k_dstep(
    int stepi,
    const float* __restrict__ target, const float* __restrict__ seq,
    const float* __restrict__ scores,
    const float* __restrict__ Wt4D, const float* __restrict__ WihD4,
    const float* __restrict__ bsD4,
    const float* __restrict__ hread, float* __restrict__ hwrite,
    float* __restrict__ cdec, float* __restrict__ out) {
  int blk = blockIdx.x;
  int bq = blk >> 4, s = blk & 15;
  int b0 = bq * 4;
  int t = threadIdx.x;
  int lane = t & 63, w = t >> 6;
  __shared__ float xs[4];
  __shared__ float hs[4][HN];
  __shared__ float P[8][4][32][4];
  // phase A: x select (+softmax/out of step-1, + argmax feedback)
  {
    int b = b0 + w;
    if (stepi == 0) {
      if (lane == 0) xs[w] = target[b * TN + 0];
    } else {
      float v0 = scores[b * LN + lane];
      float v1 = scores[b * LN + 64 + lane];
      bool m0 = (lane == 0) || (seq[b * LN + lane] != 0.f);
      bool m1 = (seq[b * LN + 64 + lane] != 0.f);
      v0 = m0 ? v0 : v0 - 1000.f;
      v1 = m1 ? v1 : v1 - 1000.f;
      float mx; int ix;
      if (v0 >= v1) { mx = v0; ix = lane; } else { mx = v1; ix = 64 + lane; }
#pragma unroll
      for (int off = 32; off >= 1; off >>= 1) {
        float ov = __shfl_down(mx, off);
        int   oi = __shfl_down(ix, off);
        if (ov > mx || (ov == mx && oi < ix)) { mx = ov; ix = oi; }
      }
      mx = __shfl(mx, 0); ix = __shfl(ix, 0);
      float e0 = __expf(v0 - mx), e1 = __expf(v1 - mx);
      float sum = e0 + e1;
#pragma unroll
      for (int off = 32; off >= 1; off >>= 1) sum += __shfl_down(sum, off);
      sum = __shfl(sum, 0);
      float inv = 1.0f / sum;
      if (s == 0) {
        out[((size_t)b * TN + stepi - 1) * LN + lane] = e0 * inv;
        out[((size_t)b * TN + stepi - 1) * LN + 64 + lane] = e1 * inv;
      }
      if (lane == 0)
        xs[w] = (stepi == 1) ? target[b * TN + 1]
                             : ((ix == 0) ? 0.1f : seq[b * LN + ix]);
    }
  }
  for (int i = t; i < 4 * HN; i += 256)
    hs[i >> 9][i & 511] = hread[(size_t)(b0 + (i >> 9)) * HN + (i & 511)];
  __syncthreads();
  // phase B: gates
  int j_idx = t & 31, kq = t >> 5;
  int j = s * 32 + j_idx;
  const float* wbase = Wt4D + ((size_t)(kq * 64) * 512 + j) * 4;
  float4 acc0 = make_float4(0, 0, 0, 0), acc1 = acc0, acc2 = acc0, acc3 = acc0;
#pragma unroll 4
  for (int kk4 = 0; kk4 < 16; ++kk4) {
    float4 h0 = *(const float4*)&hs[0][kq * 64 + kk4 * 4];
    float4 h1 = *(const float4*)&hs[1][kq * 64 + kk4 * 4];
    float4 h2 = *(const float4*)&hs[2][kq * 64 + kk4 * 4];
    float4 h3 = *(const float4*)&hs[3][kq * 64 + kk4 * 4];
    const float* wp = wbase + (size_t)(kk4 * 4) * 2048;
#pragma unroll
    for (int u = 0; u < 4; ++u) {
      float4 wv = *(const float4*)(wp + (size_t)u * 2048);
      float hu0 = (&h0.x)[u], hu1 = (&h1.x)[u], hu2 = (&h2.x)[u], hu3 = (&h3.x)[u];
      acc0.x += wv.x * hu0; acc0.y += wv.y * hu0; acc0.z += wv.z * hu0; acc0.w += wv.w * hu0;
      acc1.x += wv.x * hu1; acc1.y += wv.y * hu1; acc1.z += wv.z * hu1; acc1.w += wv.w * hu1;
      acc2.x += wv.x * hu2; acc2.y += wv.y * hu2; acc2.z += wv.z * hu2; acc2.w += wv.w * hu2;
      acc3.x += wv.x * hu3; acc3.y += wv.y * hu3; acc3.z += wv.z * hu3; acc3.w += wv.w * hu3;
    }
  }
  *(float4*)&P[kq][0][j_idx][0] = acc0;
  *(float4*)&P[kq][1][j_idx][0] = acc1;
  *(float4*)&P[kq][2][j_idx][0] = acc2;
  *(float4*)&P[kq][3][j_idx][0] = acc3;
  __syncthreads();
  if (t < 128) {
    int bb = t >> 5, ji = t & 31;
    int b = b0 + bb, jj = s * 32 + ji;
    float4 gsum = make_float4(0, 0, 0, 0);
#pragma unroll
    for (int q = 0; q < 8; ++q) {
      float4 p = *(const float4*)&P[q][bb][ji][0];
      gsum.x += p.x; gsum.y += p.y; gsum.z += p.z; gsum.w += p.w;
    }
    float x = xs[bb];
    float4 wih = *(const float4*)&WihD4[jj * 4];
    float4 b4 = *(const float4*)&bsD4[jj * 4];
    float gi = gsum.x + x * wih.x + b4.x;
    float gf = gsum.y + x * wih.y + b4.y;
    float gg = gsum.z + x * wih.z + b4.z;
    float go = gsum.w + x * wih.w + b4.w;
    float cold = cdec[(size_t)b * HN + jj];
    float cn = fsig(gf) * cold + fsig(gi) * ftanh(gg);
    float hn = fsig(go) * ftanh(cn);
    cdec[(size_t)b * HN + jj] = cn;
    hwrite[(size_t)b * HN + jj] = hn;
  }
}

// ---------- d = h_new @ Wd.T + bd ----------
__global__ __launch_bounds__(256) void k_dproj(
    const float* __restrict__ hnew, const float* __restrict__ WdT,
    const float* __restrict__ bd, float* __restrict__ dvec) {
  int blk = blockIdx.x;
  int bq = blk >> 4, s = blk & 15;
  int b0 = bq * 4;
  int t = threadIdx.x;
  int j_idx = t & 31, kq = t >> 5;
  int j = s * 32 + j_idx;
  __shared__ float hs[4][HN];
  __shared__ float Q[8][4][32];
  for (int i = t; i < 4 * HN; i += 256)
    hs[i >> 9][i & 511] = hnew[(size_t)(b0 + (i >> 9)) * HN + (i & 511)];
  __syncthreads();
  float a0 = 0, a1 = 0, a2 = 0, a3 = 0;
#pragma unroll 4
  for (int kk4 = 0; kk4 < 16; ++kk4) {
    float4 h0 = *(const float4*)&hs[0][kq * 64 + kk4 * 4];
    float4 h1 = *(const float4*)&hs[1][kq * 64 + kk4 * 4];
    float4 h2 = *(const float4*)&hs[2][kq * 64 + kk4 * 4];
    float4 h3 = *(const float4*)&hs[3][kq * 64 + kk4 * 4];
#pragma unroll
    for (int u = 0; u < 4; ++u) {
      float wv = WdT[(size_t)(kq * 64 + kk4 * 4 + u) * 512 + j];
      a0 += wv * (&h0.x)[u]; a1 += wv * (&h1.x)[u];
      a2 += wv * (&h2.x)[u]; a3 += wv * (&h3.x)[u];
    }
  }
  Q[kq][0][j_idx] = a0; Q[kq][1][j_idx] = a1; Q[kq][2][j_idx] = a2; Q[kq][3][j_idx] = a3;
  __syncthreads();
  if (t < 128) {
    int bb = t >> 5, ji = t & 31;
    int jj = s * 32 + ji;
    float d = bd[jj];
#pragma unroll
    for (int q = 0; q < 8; ++q) d += Q[q][bb][ji];
    dvec[(size_t)(b0 + bb) * HN + jj] = d;
  }
}

// ---------- fused scores: s[b][l] = v . tanh(e[b][l]@M + cv + d[b]) ----------
// grid 512 = b(64) x lt(8); block: 16 l x 512 c, 256 thr, 4x8 per thread
__global__ __launch_bounds__(256) void k_score(
    const float* __restrict__ E, const float* __restrict__ M,
    const float* __restrict__ cv, const float* __restrict__ dvec,
    const float* __restrict__ vv, float* __restrict__ scores) {
  int b = blockIdx.x >> 3, lt = blockIdx.x & 7;
  int l0 = lt * 16;
  int t = threadIdx.x;
  int ty = t >> 6, tx = t & 63;
  __shared__ float As[16][20];
  __shared__ float Bs[16][516];
  float acc[4][8];
#pragma unroll
  for (int r = 0; r < 4; ++r)
#pragma unroll
    for (int u = 0; u < 8; ++u) acc[r][u] = 0.f;
  int all = t >> 4, akk = t & 15;
  int bkr = t >> 4, bc = (t & 15) * 32;
  for (int k0 = 0; k0 < 512; k0 += 16) {
    __syncthreads();
    As[all][akk] = E[((size_t)b * LN + l0 + all) * 512 + k0 + akk];
#pragma unroll
    for (int u = 0; u < 8; ++u)
      *(float4*)&Bs[bkr][bc + u * 4] = *(const float4*)&M[(size_t)(k0 + bkr) * 512 + bc + u * 4];
    __syncthreads();
#pragma unroll
    for (int kk = 0; kk < 16; ++kk) {
      float a0 = As[ty * 4 + 0][kk];
      float a1 = As[ty * 4 + 1][kk];
      float a2 = As[ty * 4 + 2][kk];
      float a3 = As[ty * 4 + 3][kk];
      float4 bA = *(const float4*)&Bs[kk][tx * 8];
      float4 bB = *(const float4*)&Bs[kk][tx * 8 + 4];
      float bn[8] = {bA.x, bA.y, bA.z, bA.w, bB.x, bB.y, bB.z, bB.w};
#pragma unroll
      for (int u = 0; u < 8; ++u) {
        acc[0][u] += a0 * bn[u];
        acc[1][u] += a1 * bn[u];
        acc[2][u] += a2 * bn[u];
        acc[3][u] += a3 * bn[u];
      }
    }
  }
  float4 cv0 = *(const float4*)&cv[tx * 8];
  float4 cv1 = *(const float4*)&cv[tx * 8 + 4];
  float4 dv0 = *(const float4*)&dvec[(size_t)b * HN + tx * 8];
  float4 dv1 = *(const float4*)&dvec[(size_t)b * HN + tx * 8 + 4];
  float4 vA = *(const float4*)&vv[tx * 8];
  float4 vB = *(const float4*)&vv[tx * 8 + 4];
  float cvv[8] = {cv0.x + dv0.x, cv0.y + dv0.y, cv0.z + dv0.z, cv0.w + dv0.w,
                  cv1.x + dv1.x, cv1.y + dv1.y, cv1.z + dv1.z, cv1.w + dv1.w};
  float vr[8] = {vA.x, vA.y, vA.z, vA.w, vB.x, vB.y, vB.z, vB.w};
#pragma unroll
  for (int r = 0; r < 4; ++r) {
    float sacc = 0.f;
#pragma unroll
    for (int u = 0; u < 8; ++u) sacc += vr[u] * ftanh(acc[r][u] + cvv[u]);
#pragma unroll
    for (int off = 32; off >= 1; off >>= 1) sacc += __shfl_down(sacc, off);
    if (tx == 0) scores[(size_t)b * LN + l0 + ty * 4 + r] = sacc;
  }
}

// ---------- final softmax/out for step 31 ----------
__global__ __launch_bounds__(64) void k_fin(
    const float* __restrict__ scores, const float* __restrict__ seq,
    float* __restrict__ out) {
  int b = blockIdx.x, lane = threadIdx.x;
  float v0 = scores[b * LN + lane];
  float v1 = scores[b * LN + 64 + lane];
  bool m0 = (lane == 0) || (seq[b * LN + lane] != 0.f);
  bool m1 = (seq[b * LN + 64 + lane] != 0.f);
  v0 = m0 ? v0 : v0 - 1000.f;
  v1 = m1 ? v1 : v1 - 1000.f;
  float mx = fmaxf(v0, v1);
#pragma unroll
  for (int off = 32; off >= 1; off >>= 1) mx = fmaxf(mx, __shfl_down(mx, off));
  mx = __shfl(mx, 0);
  float e0 = __expf(v0 - mx), e1 = __expf(v1 - mx);
  float sum = e0 + e1;
#pragma unroll
  for (int off = 32; off >= 1; off >>= 1) sum += __shfl_down(sum, off);
  sum = __shfl(sum, 0);
  float inv = 1.0f / sum;
  out[((size_t)b * TN + 31) * LN + lane] = e0 * inv;
  out[((size_t)b * TN + 31) * LN + 64 + lane] = e1 * inv;
}

extern "C" void kernel_launch(void* const* d_in, const int* in_sizes, int n_in,
                              void* d_out, int out_size, void* d_ws, size_t ws_size,
                              hipStream_t stream) {
  const float* seq    = (const float*)d_in[0];
  const int*   seq_m  = (const int*)  d_in[1];
  const float* target = (const float*)d_in[2];
  const float* Wih_e  = (const float*)d_in[3];
  const float* Whh_e  = (const float*)d_in[4];
  const float* bih_e  = (const float*)d_in[5];
  const float* bhh_e  = (const float*)d_in[6];
  const float* Wih_d  = (const float*)d_in[7];
  const float* Whh_d  = (const float*)d_in[8];
  const float* bih_d  = (const float*)d_in[9];
  const float* bhh_d  = (const float*)d_in[10];
  const float* We     = (const float*)d_in[11];
  const float* be     = (const float*)d_in[12];
  const float* Wd     = (const float*)d_in[13];
  const float* bd     = (const float*)d_in[14];
  const float* vv     = (const float*)d_in[15];
  float* out = (float*)d_out;
  float* W = (float*)d_ws;

  size_t o = 0;
  float* Wt4E = W + o; o += 1048576;
  float* Wt4D = W + o; o += 1048576;
  float* WdT  = W + o; o += 262144;
  float* WihE4 = W + o; o += 2048;
  float* WihD4 = W + o; o += 2048;
  float* bsE4 = W + o; o += 2048;
  float* bsD4 = W + o; o += 2048;
  float* zvec = W + o; o += 512;
  unsigned int* cnt = (unsigned int*)(W + o); o += 32;
  float* cva  = W + o; o += 16384;
  float* vtmp = W + o; o += 15872;
  float* hx   = W + o; o += 65536;
  float* hdec = W + o; o += 65536;   // 2 ping-pong buffers
  float* cdec = W + o; o += 32768;
  float* dvec = W + o; o += 32768;
  float* scores = W + o; o += 8192;
  float* e    = W + o; o += 4194304;
  float* Mall = W + o;
  size_t fixed = o;
  bool mega = ws_size >= (fixed + 32ull * 262144) * sizeof(float);
  // fallback needs 3 M buffers
  // (round-2 fallback path ran in <= ws; this fallback needs less)

  k_tpack<<<256, 256, 0, stream>>>(Whh_e, Whh_d, Wt4E, Wt4D);
  k_tr<<<512, 256, 0, stream>>>(We, Wd, Mall, WdT);
  k_small<<<37, 256, 0, stream>>>(Wih_e, Wih_d, bih_e, bhh_e, bih_d, bhh_d, be,
                                  WihE4, WihD4, bsE4, bsD4, zvec, cnt, cva);
  k_enc<<<256, 512, 0, stream>>>(seq, seq_m, WihE4, Wt4E, bsE4, e, hdec, cdec, hx, cnt);

  if (mega) {
    for (int r = 0; r < 5; ++r) {
      int p = 1 << r;
      dim3 gp(4, 4, p);
      k_gemm<<<gp, 256, 0, stream>>>(Mall, Mall + (size_t)(p - 1) * 262144, zvec,
                                     Mall + (size_t)p * 262144, 262144, 0, 0, 262144);
    }
    k_cvec<<<31, 256, 0, stream>>>(be, Mall, vtmp);
    k_cpref<<<1, 512, 0, stream>>>(be, vtmp, cva);
    for (int i = 0; i < TN; ++i) {
      float* hr = hdec + (size_t)(i & 1) * 32768;
      float* hw = hdec + (size_t)((i & 1) ^ 1) * 32768;
      k_dstep<<<256, 256, 0, stream>>>(i, target, seq, scores, Wt4D, WihD4, bsD4,
                                       hr, hw, cdec, out);
      k_dproj<<<256, 256, 0, stream>>>(hw, WdT, bd, dvec);
      k_score<<<512, 256, 0, stream>>>(e, Mall + (size_t)i * 262144,
                                       cva + (size_t)i * 512, dvec, vv, scores);
    }
  } else {
    for (int i = 0; i < TN; ++i) {
      const float* Mi; const float* ci;
      if (i == 0) { Mi = Mall; ci = cva; }
      else {
        float* Msrc = (i == 1) ? Mall : Mall + (size_t)(1 + (i & 1)) * 262144;
        float* Mdst = Mall + (size_t)(1 + ((i - 1) & 1)) * 262144;
        dim3 gp(4, 4, 1);
        k_gemm<<<gp, 256, 0, stream>>>(Msrc, Mall, zvec, Mdst, 0, 0, 0, 0);
        k_cstep<<<1, 512, 0, stream>>>(cva + (size_t)((i - 1) & 1) * 512, Mall, be,
                                       cva + (size_t)(i & 1) * 512);
        Mi = Mdst; ci = cva + (size_t)(i & 1) * 512;
      }
      float* hr = hdec + (size_t)(i & 1) * 32768;
      float* hw = hdec + (size_t)((i & 1) ^ 1) * 32768;
      k_dstep<<<256, 256, 0, stream>>>(i, target, seq, scores, Wt4D, WihD4, bsD4,
                                       hr, hw, cdec, out);
      k_dproj<<<256, 256, 0, stream>>>(hw, WdT, bd, dvec);
      k_score<<<512, 256, 0, stream>>>(e, Mi, ci, dvec, vv, scores);
    }
  }
  k_fin<<<64, 64, 0, stream>>>(scores, seq, out);
}

// Round 4
// 3809.367 us; speedup vs baseline: 4.8031x; 1.6366x over previous
//
#include <hip/hip_runtime.h>
#include <cstddef>
#include <cstdint>

#define BN 64
#define LN 128
#define TN 32
#define HN 512
#define GN 2048

typedef __attribute__((ext_vector_type(8))) short short8;
typedef __attribute__((ext_vector_type(4))) float f32x4;

__device__ __forceinline__ float fsig(float x)  { return 1.0f / (1.0f + __expf(-x)); }
__device__ __forceinline__ float ftanh(float x) { return 1.0f - 2.0f / (__expf(2.0f * x) + 1.0f); }

__device__ __forceinline__ unsigned short bf16r(float v) {
  unsigned int u = __float_as_uint(v);
  u += 0x7FFFu + ((u >> 16) & 1u);
  return (unsigned short)(u >> 16);
}
__device__ __forceinline__ float bf2f(unsigned short h) {
  return __uint_as_float((unsigned int)h << 16);
}

// ---------- gate-packed transpose: Wt4[k][c][g] = Whh[g*512+c][k] ----------
__global__ __launch_bounds__(256) void k_tpack(
    const float* __restrict__ Whh_e, const float* __restrict__ Whh_d,
    float* __restrict__ Wt4E, float* __restrict__ Wt4D) {
  int blk = blockIdx.x;
  const float* src = (blk >> 7) ? Whh_d : Whh_e;
  float* dst = (blk >> 7) ? Wt4D : Wt4E;
  int r = blk & 127;
  int kt = r >> 4, ct = r & 15;
  int t = threadIdx.x;
  __shared__ float L[4][32][65];
  int cl = t >> 3, k8 = (t & 7) * 8;
#pragma unroll
  for (int g = 0; g < 4; ++g) {
    float4 a = *(const float4*)&src[(size_t)(g * 512 + ct * 32 + cl) * 512 + kt * 64 + k8];
    float4 b = *(const float4*)&src[(size_t)(g * 512 + ct * 32 + cl) * 512 + kt * 64 + k8 + 4];
    L[g][cl][k8 + 0] = a.x; L[g][cl][k8 + 1] = a.y; L[g][cl][k8 + 2] = a.z; L[g][cl][k8 + 3] = a.w;
    L[g][cl][k8 + 4] = b.x; L[g][cl][k8 + 5] = b.y; L[g][cl][k8 + 6] = b.z; L[g][cl][k8 + 7] = b.w;
  }
  __syncthreads();
  int kl = t >> 2, c8 = (t & 3) * 8;
#pragma unroll
  for (int i = 0; i < 8; ++i) {
    int c = c8 + i;
    float4 v = make_float4(L[0][c][kl], L[1][c][kl], L[2][c][kl], L[3][c][kl]);
    *(float4*)&dst[((size_t)(kt * 64 + kl) * 512 + ct * 32 + c) * 4] = v;
  }
}

// ---------- plain 512x512 transpose ----------
__global__ __launch_bounds__(256) void k_tr(
    const float* __restrict__ We, const float* __restrict__ Wd,
    float* __restrict__ M0, float* __restrict__ WdT) {
  int blk = blockIdx.x;
  const float* src = (blk >> 8) ? Wd : We;
  float* dst = (blk >> 8) ? WdT : M0;
  int r = blk & 255;
  int rt = r >> 4, ct = r & 15;
  int t = threadIdx.x;
  __shared__ float T[32][33];
  int jl = t >> 3, m4 = (t & 7) * 4;
  float4 a = *(const float4*)&src[(size_t)(ct * 32 + jl) * 512 + rt * 32 + m4];
  T[jl][m4 + 0] = a.x; T[jl][m4 + 1] = a.y; T[jl][m4 + 2] = a.z; T[jl][m4 + 3] = a.w;
  __syncthreads();
  int ml = t >> 3, j4 = (t & 7) * 4;
  float4 v = make_float4(T[j4 + 0][ml], T[j4 + 1][ml], T[j4 + 2][ml], T[j4 + 3][ml]);
  *(float4*)&dst[(size_t)(rt * 32 + ml) * 512 + ct * 32 + j4] = v;
}

// ---------- small packs ----------
__global__ __launch_bounds__(256) void k_small(
    const float* __restrict__ Wih_e, const float* __restrict__ Wih_d,
    const float* __restrict__ bih_e, const float* __restrict__ bhh_e,
    const float* __restrict__ bih_d, const float* __restrict__ bhh_d,
    const float* __restrict__ be,
    float* __restrict__ WihE4, float* __restrict__ WihD4,
    float* __restrict__ bsE4, float* __restrict__ bsD4,
    float* __restrict__ zvec, unsigned int* __restrict__ cnt,
    float* __restrict__ cva0) {
  int idx = blockIdx.x * 256 + threadIdx.x;
  if (idx < 2048) { int c = idx >> 2, g = idx & 3; WihE4[idx] = Wih_e[g * 512 + c]; }
  else if (idx < 4096) { int r = idx - 2048; int c = r >> 2, g = r & 3; WihD4[r] = Wih_d[g * 512 + c]; }
  else if (idx < 6144) { int r = idx - 4096; int c = r >> 2, g = r & 3; bsE4[r] = bih_e[g * 512 + c] + bhh_e[g * 512 + c]; }
  else if (idx < 8192) { int r = idx - 6144; int c = r >> 2, g = r & 3; bsD4[r] = bih_d[g * 512 + c] + bhh_d[g * 512 + c]; }
  else if (idx < 8704) { zvec[idx - 8192] = 0.f; }
  else if (idx < 8736) { cnt[idx - 8704] = 0u; }
  else if (idx < 9248) { cva0[idx - 8736] = be[idx - 8736]; }
}

// ---------- encoder: 256 persistent blocks, group pinned to one XCD ----------
__global__ __launch_bounds__(512) void k_enc(
    const float* __restrict__ seq, const int* __restrict__ seq_m,
    const float* __restrict__ WihE4, const float* __restrict__ Wt4E,
    const float* __restrict__ bsE4,
    float* __restrict__ e, float* __restrict__ hdec, float* __restrict__ cdec,
    float* __restrict__ hx, unsigned int* __restrict__ cnt) {
  int blk = blockIdx.x;
  // group -> same XCD under blockIdx%8 dispatch heuristic (correctness-independent)
  int g = ((blk & 7) << 1) | ((blk >> 3) & 1);
  int s = blk >> 4;
  int b0 = g * 4;
  int t = threadIdx.x;
  int c_idx = t & 31, kq = t >> 5;
  int c = s * 32 + c_idx;
  __shared__ float hs[4][HN];
  __shared__ float P[16][4][32][4];
  for (int i = t; i < 4 * HN; i += 512) ((float*)hs)[i] = 0.f;
  int ebb = t >> 5, eci = t & 31;
  float cstate = 0.f;
  float4 wih = make_float4(0, 0, 0, 0), bs4 = make_float4(0, 0, 0, 0);
  int len = -2;
  if (t < 128) {
    int ec = s * 32 + eci;
    wih = *(const float4*)&WihE4[ec * 4];
    bs4 = *(const float4*)&bsE4[ec * 4];
    len = seq_m[b0 + ebb] - 1;
  }
  unsigned int* cg = cnt + g;
  const float* wbase = Wt4E + ((size_t)(kq * 32) * 512 + c) * 4;
  __syncthreads();
  for (int st = 0; st < LN; ++st) {
    if (st > 0) {
      // t0's agent-acquire (prev iter) invalidated L1/L2 -> plain vector loads are fresh
      const float4* src4 = (const float4*)(hx + (size_t)((st & 1) ^ 1) * (BN * HN));
      ((float4*)hs)[t] = src4[(size_t)b0 * 128 + t];
      __syncthreads();
    }
    float4 acc0 = make_float4(0, 0, 0, 0), acc1 = acc0, acc2 = acc0, acc3 = acc0;
#pragma unroll
    for (int kk4 = 0; kk4 < 8; ++kk4) {
      float4 h0 = *(const float4*)&hs[0][kq * 32 + kk4 * 4];
      float4 h1 = *(const float4*)&hs[1][kq * 32 + kk4 * 4];
      float4 h2 = *(const float4*)&hs[2][kq * 32 + kk4 * 4];
      float4 h3 = *(const float4*)&hs[3][kq * 32 + kk4 * 4];
      const float* wp = wbase + (size_t)(kk4 * 4) * 2048;
#pragma unroll
      for (int u = 0; u < 4; ++u) {
        float4 w = *(const float4*)(wp + (size_t)u * 2048);
        float hu0 = (&h0.x)[u], hu1 = (&h1.x)[u], hu2 = (&h2.x)[u], hu3 = (&h3.x)[u];
        acc0.x += w.x * hu0; acc0.y += w.y * hu0; acc0.z += w.z * hu0; acc0.w += w.w * hu0;
        acc1.x += w.x * hu1; acc1.y += w.y * hu1; acc1.z += w.z * hu1; acc1.w += w.w * hu1;
        acc2.x += w.x * hu2; acc2.y += w.y * hu2; acc2.z += w.z * hu2; acc2.w += w.w * hu2;
        acc3.x += w.x * hu3; acc3.y += w.y * hu3; acc3.z += w.z * hu3; acc3.w += w.w * hu3;
      }
    }
    *(float4*)&P[kq][0][c_idx][0] = acc0;
    *(float4*)&P[kq][1][c_idx][0] = acc1;
    *(float4*)&P[kq][2][c_idx][0] = acc2;
    *(float4*)&P[kq][3][c_idx][0] = acc3;
    __syncthreads();
    if (t < 128) {
      int b = b0 + ebb, ec = s * 32 + eci;
      float4 gsum = make_float4(0, 0, 0, 0);
#pragma unroll
      for (int q = 0; q < 16; ++q) {
        float4 p = *(const float4*)&P[q][ebb][eci][0];
        gsum.x += p.x; gsum.y += p.y; gsum.z += p.z; gsum.w += p.w;
      }
      float x = seq[b * LN + st];
      float gi = gsum.x + x * wih.x + bs4.x;
      float gf = gsum.y + x * wih.y + bs4.y;
      float gg = gsum.z + x * wih.z + bs4.z;
      float go = gsum.w + x * wih.w + bs4.w;
      float cn = fsig(gf) * cstate + fsig(gi) * ftanh(gg);
      cstate = cn;
      float hn = fsig(go) * ftanh(cn);
      e[((size_t)b * LN + st) * HN + ec] = hn;
      hx[(size_t)(st & 1) * (BN * HN) + (size_t)b * HN + ec] = hn;
      if (st == len) { hdec[(size_t)b * HN + ec] = hn; cdec[(size_t)b * HN + ec] = cn; }
    }
    __syncthreads();
    if (t == 0) {
      __threadfence();
      atomicAdd(cg, 1u);
      unsigned int tgt = 16u * (unsigned)(st + 1);
      while (__hip_atomic_load(cg, __ATOMIC_ACQUIRE, __HIP_MEMORY_SCOPE_AGENT) < tgt)
        __builtin_amdgcn_s_sleep(2);
    }
    __syncthreads();
  }
}

// ---------- generic 512-K GEMM (M-power doubling) ----------
__global__ __launch_bounds__(256) void k_gemm(
    const float* __restrict__ Ab, const float* __restrict__ Bb,
    const float* __restrict__ Cvb, float* __restrict__ Ob,
    size_t Asz, size_t Bsz, size_t Cvsz, size_t Osz) {
  int z = blockIdx.z;
  const float* A = Ab + (size_t)z * Asz;
  const float* B = Bb + (size_t)z * Bsz;
  const float* CV = Cvb + (size_t)z * Cvsz;
  float* O = Ob + (size_t)z * Osz;
  int tn = blockIdx.x * 128;
  int tm = blockIdx.y * 128;
  int t = threadIdx.x;
  __shared__ float As[8][132];
  __shared__ float Bs[8][132];
  int ar = t >> 1, ak4 = (t & 1) * 4;
  int bk2 = t >> 5, bj = (t & 31) * 4;
  int ty = t >> 4, tx = t & 15;
  float acc[8][8];
#pragma unroll
  for (int i = 0; i < 8; ++i)
#pragma unroll
    for (int j = 0; j < 8; ++j) acc[i][j] = 0.f;
  for (int k0 = 0; k0 < 512; k0 += 8) {
    float4 av = *(const float4*)&A[(size_t)(tm + ar) * 512 + k0 + ak4];
    float4 bv = *(const float4*)&B[(size_t)(k0 + bk2) * 512 + tn + bj];
    __syncthreads();
    As[ak4 + 0][ar] = av.x; As[ak4 + 1][ar] = av.y; As[ak4 + 2][ar] = av.z; As[ak4 + 3][ar] = av.w;
    *(float4*)&Bs[bk2][bj] = bv;
    __syncthreads();
#pragma unroll
    for (int kk = 0; kk < 8; ++kk) {
      float4 A0 = *(const float4*)&As[kk][ty * 8];
      float4 A1 = *(const float4*)&As[kk][ty * 8 + 4];
      float4 B0 = *(const float4*)&Bs[kk][tx * 8];
      float4 B1 = *(const float4*)&Bs[kk][tx * 8 + 4];
      float am[8] = {A0.x, A0.y, A0.z, A0.w, A1.x, A1.y, A1.z, A1.w};
      float bn[8] = {B0.x, B0.y, B0.z, B0.w, B1.x, B1.y, B1.z, B1.w};
#pragma unroll
      for (int i2 = 0; i2 < 8; ++i2)
#pragma unroll
        for (int j2 = 0; j2 < 8; ++j2) acc[i2][j2] += am[i2] * bn[j2];
    }
  }
  float4 cv0 = *(const float4*)&CV[tn + tx * 8];
  float4 cv1 = *(const float4*)&CV[tn + tx * 8 + 4];
  float cvv[8] = {cv0.x, cv0.y, cv0.z, cv0.w, cv1.x, cv1.y, cv1.z, cv1.w};
#pragma unroll
  for (int r = 0; r < 8; ++r) {
    float4 o0, o1;
    o0.x = acc[r][0] + cvv[0]; o0.y = acc[r][1] + cvv[1]; o0.z = acc[r][2] + cvv[2]; o0.w = acc[r][3] + cvv[3];
    o1.x = acc[r][4] + cvv[4]; o1.y = acc[r][5] + cvv[5]; o1.z = acc[r][6] + cvv[6]; o1.w = acc[r][7] + cvv[7];
    *(float4*)&O[(size_t)(tm + ty * 8 + r) * 512 + tn + tx * 8]     = o0;
    *(float4*)&O[(size_t)(tm + ty * 8 + r) * 512 + tn + tx * 8 + 4] = o1;
  }
}

// ---------- vtmp[k] = be @ M_k ----------
__global__ __launch_bounds__(256) void k_cvec(
    const float* __restrict__ be, const float* __restrict__ Mall, float* __restrict__ vtmp) {
  int k = blockIdx.x, t = threadIdx.x;
  const float* M = Mall + (size_t)k * 262144;
  float a0 = 0.f, a1 = 0.f;
  for (int m = 0; m < 512; ++m) {
    float bm = be[m];
    a0 += bm * M[(size_t)m * 512 + t];
    a1 += bm * M[(size_t)m * 512 + t + 256];
  }
  vtmp[(size_t)k * 512 + t] = a0;
  vtmp[(size_t)k * 512 + t + 256] = a1;
}

__global__ __launch_bounds__(512) void k_cpref(
    const float* __restrict__ be, const float* __restrict__ vtmp, float* __restrict__ cva) {
  int j = threadIdx.x;
  float run = be[j];
  for (int i = 0; i < 32; ++i) {
    cva[(size_t)i * 512 + j] = run;
    if (i < 31) run += vtmp[(size_t)i * 512 + j];
  }
}

__global__ __launch_bounds__(512) void k_cstep(
    const float* __restrict__ csrc, const float* __restrict__ M0,
    const float* __restrict__ be, float* __restrict__ cdst) {
  int j = threadIdx.x;
  float a = be[j];
  for (int m = 0; m < 512; ++m) a += csrc[m] * M0[(size_t)m * 512 + j];
  cdst[j] = a;
}

// ---------- pack e -> bf16 hi/lo ----------
__global__ __launch_bounds__(256) void k_packE(
    const float* __restrict__ e, unsigned short* __restrict__ ehi,
    unsigned short* __restrict__ elo) {
  size_t i4 = (size_t)blockIdx.x * 256 + threadIdx.x;
  float4 v = ((const float4*)e)[i4];
  unsigned short h[4], l[4];
#pragma unroll
  for (int u = 0; u < 4; ++u) {
    float f = (&v.x)[u];
    h[u] = bf16r(f);
    l[u] = bf16r(f - bf2f(h[u]));
  }
  *(ushort4*)&ehi[i4 * 4] = make_ushort4(h[0], h[1], h[2], h[3]);
  *(ushort4*)&elo[i4 * 4] = make_ushort4(l[0], l[1], l[2], l[3]);
}

// ---------- pack M_i -> transposed bf16 hi/lo: MT[i][n][k] ----------
__global__ __launch_bounds__(256) void k_packM(
    const float* __restrict__ Mall, unsigned short* __restrict__ MhiT,
    unsigned short* __restrict__ MloT) {
  int i = blockIdx.y;
  int tile = blockIdx.x;
  int kt = tile >> 4, nt = tile & 15;
  int t = threadIdx.x;
  __shared__ unsigned short Lh[32][36];
  __shared__ unsigned short Ll[32][36];
  int kl = t >> 3, n4 = (t & 7) * 4;
  float4 v = *(const float4*)&Mall[(size_t)i * 262144 + (size_t)(kt * 32 + kl) * 512 + nt * 32 + n4];
#pragma unroll
  for (int u = 0; u < 4; ++u) {
    float f = (&v.x)[u];
    unsigned short h = bf16r(f);
    Lh[kl][n4 + u] = h;
    Ll[kl][n4 + u] = bf16r(f - bf2f(h));
  }
  __syncthreads();
  int nl = t >> 3, k4 = (t & 7) * 4;
  size_t dst = (size_t)i * 262144 + (size_t)(nt * 32 + nl) * 512 + kt * 32 + k4;
  *(ushort4*)&MhiT[dst] = make_ushort4(Lh[k4][nl], Lh[k4 + 1][nl], Lh[k4 + 2][nl], Lh[k4 + 3][nl]);
  *(ushort4*)&MloT[dst] = make_ushort4(Ll[k4][nl], Ll[k4 + 1][nl], Ll[k4 + 2][nl], Ll[k4 + 3][nl]);
}

// ---------- MFMA split-bf16 fused score kernel ----------
// grid 256 = b(64) x lt(4); block 256 thr = 4 waves; wave w covers cols [w*128,(w+1)*128)
// scores[b][l] = sum_h v[h] * tanh( (e@M)[l][h] + cv[h] + d[b][h] )
__global__ __launch_bounds__(256, 2) void k_score_mfma(
    const unsigned short* __restrict__ ehi, const unsigned short* __restrict__ elo,
    const unsigned short* __restrict__ Mhi, const unsigned short* __restrict__ Mlo,
    const float* __restrict__ cv, const float* __restrict__ dvec,
    const float* __restrict__ vvp, float* __restrict__ scores) {
  int b = blockIdx.x >> 2, lt = blockIdx.x & 3;
  int l0 = lt * 32;
  int t = threadIdx.x;
  int w = t >> 6, lane = t & 63;
  int m = lane & 15, quad = lane >> 4;
  __shared__ unsigned short Bh[512][40];
  __shared__ unsigned short Bl[512][40];
  __shared__ float pw[4][32];
  f32x4 acc[2][8];
#pragma unroll
  for (int mf = 0; mf < 2; ++mf)
#pragma unroll
    for (int nt = 0; nt < 8; ++nt) acc[mf][nt] = (f32x4){0.f, 0.f, 0.f, 0.f};
  const size_t arow = ((size_t)b * 128 + l0) * 512;
  int sn = t >> 2, sp = t & 3;
  for (int kc = 0; kc < 16; ++kc) {
    __syncthreads();
#pragma unroll
    for (int p = 0; p < 8; ++p) {
      int n = p * 64 + sn;
      size_t src = (size_t)n * 512 + kc * 32 + sp * 8;
      *(uint4*)&Bh[n][sp * 8] = *(const uint4*)&Mhi[src];
      *(uint4*)&Bl[n][sp * 8] = *(const uint4*)&Mlo[src];
    }
    __syncthreads();
    short8 ah[2], al[2];
#pragma unroll
    for (int mf = 0; mf < 2; ++mf) {
      size_t aoff = arow + (size_t)(mf * 16 + m) * 512 + kc * 32 + quad * 8;
      ah[mf] = *(const short8*)&ehi[aoff];
      al[mf] = *(const short8*)&elo[aoff];
    }
#pragma unroll
    for (int nt = 0; nt < 8; ++nt) {
      int n = w * 128 + nt * 16 + m;
      short8 bh = *(const short8*)&Bh[n][quad * 8];
      short8 bl = *(const short8*)&Bl[n][quad * 8];
#pragma unroll
      for (int mf = 0; mf < 2; ++mf) {
        acc[mf][nt] = __builtin_amdgcn_mfma_f32_16x16x32_bf16(ah[mf], bh, acc[mf][nt], 0, 0, 0);
        acc[mf][nt] = __builtin_amdgcn_mfma_f32_16x16x32_bf16(ah[mf], bl, acc[mf][nt], 0, 0, 0);
        acc[mf][nt] = __builtin_amdgcn_mfma_f32_16x16x32_bf16(al[mf], bh, acc[mf][nt], 0, 0, 0);
      }
    }
  }
  // epilogue: X + cv + d -> tanh -> *v -> sum over cols
  float cvd[8], vr[8];
#pragma unroll
  for (int nt = 0; nt < 8; ++nt) {
    int c = w * 128 + nt * 16 + m;
    cvd[nt] = cv[c] + dvec[(size_t)b * HN + c];
    vr[nt] = vvp[c];
  }
#pragma unroll
  for (int mf = 0; mf < 2; ++mf)
#pragma unroll
    for (int r = 0; r < 4; ++r) {
      float s = 0.f;
#pragma unroll
      for (int nt = 0; nt < 8; ++nt) s += vr[nt] * ftanh(acc[mf][nt][r] + cvd[nt]);
      s += __shfl_xor(s, 1);
      s += __shfl_xor(s, 2);
      s += __shfl_xor(s, 4);
      s += __shfl_xor(s, 8);
      if (m == 0) pw[w][mf * 16 + quad * 4 + r] = s;
    }
  __syncthreads();
  if (t < 32)
    scores[(size_t)b * LN + l0 + t] = pw[0][t] + pw[1][t] + pw[2][t] + pw[3][t];
}

// ---------- fp32 fused score (fallback tiers) ----------
__global__ __launch_bounds__(256) void k_score(
    const float* __restrict__ E, const float* __restrict__ M,
    const float* __restrict__ cv, const float* __restrict__ dvec,
    const float* __restrict__ vv, float* __restrict__ scores) {
  int b = blockIdx.x >> 3, lt = blockIdx.x & 7;
  int l0 = lt * 16;
  int t = threadIdx.x;
  int ty = t >> 6, tx = t & 63;
  __shared__ float As[16][20];
  __shared__ float Bs[16][516];
  float acc[4][8];
#pragma unroll
  for (int r = 0; r < 4; ++r)
#pragma unroll
    for (int u = 0; u < 8; ++u) acc[r][u] = 0.f;
  int all = t >> 4, akk = t & 15;
  int bkr = t >> 4, bc = (t & 15) * 32;
  for (int k0 = 0; k0 < 512; k0 += 16) {
    __syncthreads();
    As[all][akk] = E[((size_t)b * LN + l0 + all) * 512 + k0 + akk];
#pragma unroll
    for (int u = 0; u < 8; ++u)
      *(float4*)&Bs[bkr][bc + u * 4] = *(const float4*)&M[(size_t)(k0 + bkr) * 512 + bc + u * 4];
    __syncthreads();
#pragma unroll
    for (int kk = 0; kk < 16; ++kk) {
      float a0 = As[ty * 4 + 0][kk];
      float a1 = As[ty * 4 + 1][kk];
      float a2 = As[ty * 4 + 2][kk];
      float a3 = As[ty * 4 + 3][kk];
      float4 bA = *(const float4*)&Bs[kk][tx * 8];
      float4 bB = *(const float4*)&Bs[kk][tx * 8 + 4];
      float bn[8] = {bA.x, bA.y, bA.z, bA.w, bB.x, bB.y, bB.z, bB.w};
#pragma unroll
      for (int u = 0; u < 8; ++u) {
        acc[0][u] += a0 * bn[u];
        acc[1][u] += a1 * bn[u];
        acc[2][u] += a2 * bn[u];
        acc[3][u] += a3 * bn[u];
      }
    }
  }
  float4 cv0 = *(const float4*)&cv[tx * 8];
  float4 cv1 = *(const float4*)&cv[tx * 8 + 4];
  float4 dv0 = *(const float4*)&dvec[(size_t)b * HN + tx * 8];
  float4 dv1 = *(const float4*)&dvec[(size_t)b * HN + tx * 8 + 4];
  float4 vA = *(const float4*)&vv[tx * 8];
  float4 vB = *(const float4*)&vv[tx * 8 + 4];
  float cvv[8] = {cv0.x + dv0.x, cv0.y + dv0.y, cv0.z + dv0.z, cv0.w + dv0.w,
                  cv1.x + dv1.x, cv1.y + dv1.y, cv1.z + dv1.z, cv1.w + dv1.w};
  float vr[8] = {vA.x, vA.y, vA.z, vA.w, vB.x, vB.y, vB.z, vB.w};
#pragma unroll
  for (int r = 0; r < 4; ++r) {
    float sacc = 0.f;
#pragma unroll
    for (int u = 0; u < 8; ++u) sacc += vr[u] * ftanh(acc[r][u] + cvv[u]);
#pragma unroll
    for (int off = 32; off >= 1; off >>= 1) sacc += __shfl_down(sacc, off);
    if (tx == 0) scores[(size_t)b * LN + l0 + ty * 4 + r] = sacc;
  }
}

// ---------- decoder LSTM step (+ prev-step softmax/argmax/out) ----------
__global__ __launch_bounds__(256) void k_dstep(
    int stepi,
    const float* __restrict__ target, const float* __restrict__ seq,
    const float* __restrict__ scores,
    const float* __restrict__ Wt4D, const float* __restrict__ WihD4,
    const float* __restrict__ bsD4,
    const float* __restrict__ hread, float* __restrict__ hwrite,
    float* __restrict__ cdec, float* __restrict__ out) {
  int blk = blockIdx.x;
  int bq = blk >> 4, s = blk & 15;
  int b0 = bq * 4;
  int t = threadIdx.x;
  int lane = t & 63, w = t >> 6;
  __shared__ float xs[4];
  __shared__ float hs[4][HN];
  __shared__ float P[8][4][32][4];
  {
    int b = b0 + w;
    if (stepi == 0) {
      if (lane == 0) xs[w] = target[b * TN + 0];
    } else {
      float v0 = scores[b * LN + lane];
      float v1 = scores[b * LN + 64 + lane];
      bool m0 = (lane == 0) || (seq[b * LN + lane] != 0.f);
      bool m1 = (seq[b * LN + 64 + lane] != 0.f);
      v0 = m0 ? v0 : v0 - 1000.f;
      v1 = m1 ? v1 : v1 - 1000.f;
      float mx; int ix;
      if (v0 >= v1) { mx = v0; ix = lane; } else { mx = v1; ix = 64 + lane; }
#pragma unroll
      for (int off = 32; off >= 1; off >>= 1) {
        float ov = __shfl_down(mx, off);
        int   oi = __shfl_down(ix, off);
        if (ov > mx || (ov == mx && oi < ix)) { mx = ov; ix = oi; }
      }
      mx = __shfl(mx, 0); ix = __shfl(ix, 0);
      float e0 = __expf(v0 - mx), e1 = __expf(v1 - mx);
      float sum = e0 + e1;
#pragma unroll
      for (int off = 32; off >= 1; off >>= 1) sum += __shfl_down(sum, off);
      sum = __shfl(sum, 0);
      float inv = 1.0f / sum;
      if (s == 0) {
        out[((size_t)b * TN + stepi - 1) * LN + lane] = e0 * inv;
        out[((size_t)b * TN + stepi - 1) * LN + 64 + lane] = e1 * inv;
      }
      if (lane == 0)
        xs[w] = (stepi == 1) ? target[b * TN + 1]
                             : ((ix == 0) ? 0.1f : seq[b * LN + ix]);
    }
  }
  for (int i = t; i < 4 * HN; i += 256)
    hs[i >> 9][i & 511] = hread[(size_t)(b0 + (i >> 9)) * HN + (i & 511)];
  __syncthreads();
  int j_idx = t & 31, kq = t >> 5;
  int j = s * 32 + j_idx;
  const float* wbase = Wt4D + ((size_t)(kq * 64) * 512 + j) * 4;
  float4 acc0 = make_float4(0, 0, 0, 0), acc1 = acc0, acc2 = acc0, acc3 = acc0;
#pragma unroll 4
  for (int kk4 = 0; kk4 < 16; ++kk4) {
    float4 h0 = *(const float4*)&hs[0][kq * 64 + kk4 * 4];
    float4 h1 = *(const float4*)&hs[1][kq * 64 + kk4 * 4];
    float4 h2 = *(const float4*)&hs[2][kq * 64 + kk4 * 4];
    float4 h3 = *(const float4*)&hs[3][kq * 64 + kk4 * 4];
    const float* wp = wbase + (size_t)(kk4 * 4) * 2048;
#pragma unroll
    for (int u = 0; u < 4; ++u) {
      float4 wv = *(const float4*)(wp + (size_t)u * 2048);
      float hu0 = (&h0.x)[u], hu1 = (&h1.x)[u], hu2 = (&h2.x)[u], hu3 = (&h3.x)[u];
      acc0.x += wv.x * hu0; acc0.y += wv.y * hu0; acc0.z += wv.z * hu0; acc0.w += wv.w * hu0;
      acc1.x += wv.x * hu1; acc1.y += wv.y * hu1; acc1.z += wv.z * hu1; acc1.w += wv.w * hu1;
      acc2.x += wv.x * hu2; acc2.y += wv.y * hu2; acc2.z += wv.z * hu2; acc2.w += wv.w * hu2;
      acc3.x += wv.x * hu3; acc3.y += wv.y * hu3; acc3.z += wv.z * hu3; acc3.w += wv.w * hu3;
    }
  }
  *(float4*)&P[kq][0][j_idx][0] = acc0;
  *(float4*)&P[kq][1][j_idx][0] = acc1;
  *(float4*)&P[kq][2][j_idx][0] = acc2;
  *(float4*)&P[kq][3][j_idx][0] = acc3;
  __syncthreads();
  if (t < 128) {
    int bb = t >> 5, ji = t & 31;
    int b = b0 + bb, jj = s * 32 + ji;
    float4 gsum = make_float4(0, 0, 0, 0);
#pragma unroll
    for (int q = 0; q < 8; ++q) {
      float4 p = *(const float4*)&P[q][bb][ji][0];
      gsum.x += p.x; gsum.y += p.y; gsum.z += p.z; gsum.w += p.w;
    }
    float x = xs[bb];
    float4 wih = *(const float4*)&WihD4[jj * 4];
    float4 b4 = *(const float4*)&bsD4[jj * 4];
    float gi = gsum.x + x * wih.x + b4.x;
    float gf = gsum.y + x * wih.y + b4.y;
    float gg = gsum.z + x * wih.z + b4.z;
    float go = gsum.w + x * wih.w + b4.w;
    float cold = cdec[(size_t)b * HN + jj];
    float cn = fsig(gf) * cold + fsig(gi) * ftanh(gg);
    float hn = fsig(go) * ftanh(cn);
    cdec[(size_t)b * HN + jj] = cn;
    hwrite[(size_t)b * HN + jj] = hn;
  }
}

// ---------- d = h_new @ Wd.T + bd ----------
__global__ __launch_bounds__(256) void k_dproj(
    const float* __restrict__ hnew, const float* __restrict__ WdT,
    const float* __restrict__ bd, float* __restrict__ dvec) {
  int blk = blockIdx.x;
  int bq = blk >> 4, s = blk & 15;
  int b0 = bq * 4;
  int t = threadIdx.x;
  int j_idx = t & 31, kq = t >> 5;
  int j = s * 32 + j_idx;
  __shared__ float hs[4][HN];
  __shared__ float Q[8][4][32];
  for (int i = t; i < 4 * HN; i += 256)
    hs[i >> 9][i & 511] = hnew[(size_t)(b0 + (i >> 9)) * HN + (i & 511)];
  __syncthreads();
  float a0 = 0, a1 = 0, a2 = 0, a3 = 0;
#pragma unroll 4
  for (int kk4 = 0; kk4 < 16; ++kk4) {
    float4 h0 = *(const float4*)&hs[0][kq * 64 + kk4 * 4];
    float4 h1 = *(const float4*)&hs[1][kq * 64 + kk4 * 4];
    float4 h2 = *(const float4*)&hs[2][kq * 64 + kk4 * 4];
    float4 h3 = *(const float4*)&hs[3][kq * 64 + kk4 * 4];
#pragma unroll
    for (int u = 0; u < 4; ++u) {
      float wv = WdT[(size_t)(kq * 64 + kk4 * 4 + u) * 512 + j];
      a0 += wv * (&h0.x)[u]; a1 += wv * (&h1.x)[u];
      a2 += wv * (&h2.x)[u]; a3 += wv * (&h3.x)[u];
    }
  }
  Q[kq][0][j_idx] = a0; Q[kq][1][j_idx] = a1; Q[kq][2][j_idx] = a2; Q[kq][3][j_idx] = a3;
  __syncthreads();
  if (t < 128) {
    int bb = t >> 5, ji = t & 31;
    int jj = s * 32 + ji;
    float d = bd[jj];
#pragma unroll
    for (int q = 0; q < 8; ++q) d += Q[q][bb][ji];
    dvec[(size_t)(b0 + bb) * HN + jj] = d;
  }
}

// ---------- final softmax/out for step 31 ----------
__global__ __launch_bounds__(64) void k_fin(
    const float* __restrict__ scores, const float* __restrict__ seq,
    float* __restrict__ out) {
  int b = blockIdx.x, lane = threadIdx.x;
  float v0 = scores[b * LN + lane];
  float v1 = scores[b * LN + 64 + lane];
  bool m0 = (lane == 0) || (seq[b * LN + lane] != 0.f);
  bool m1 = (seq[b * LN + 64 + lane] != 0.f);
  v0 = m0 ? v0 : v0 - 1000.f;
  v1 = m1 ? v1 : v1 - 1000.f;
  float mx = fmaxf(v0, v1);
#pragma unroll
  for (int off = 32; off >= 1; off >>= 1) mx = fmaxf(mx, __shfl_down(mx, off));
  mx = __shfl(mx, 0);
  float e0 = __expf(v0 - mx), e1 = __expf(v1 - mx);
  float sum = e0 + e1;
#pragma unroll
  for (int off = 32; off >= 1; off >>= 1) sum += __shfl_down(sum, off);
  sum = __shfl(sum, 0);
  float inv = 1.0f / sum;
  out[((size_t)b * TN + 31) * LN + lane] = e0 * inv;
  out[((size_t)b * TN + 31) * LN + 64 + lane] = e1 * inv;
}

extern "C" void kernel_launch(void* const* d_in, const int* in_sizes, int n_in,
                              void* d_out, int out_size, void* d_ws, size_t ws_size,
                              hipStream_t stream) {
  const float* seq    = (const float*)d_in[0];
  const int*   seq_m  = (const int*)  d_in[1];
  const float* target = (const float*)d_in[2];
  const float* Wih_e  = (const float*)d_in[3];
  const float* Whh_e  = (const float*)d_in[4];
  const float* bih_e  = (const float*)d_in[5];
  const float* bhh_e  = (const float*)d_in[6];
  const float* Wih_d  = (const float*)d_in[7];
  const float* Whh_d  = (const float*)d_in[8];
  const float* bih_d  = (const float*)d_in[9];
  const float* bhh_d  = (const float*)d_in[10];
  const float* We     = (const float*)d_in[11];
  const float* be     = (const float*)d_in[12];
  const float* Wd     = (const float*)d_in[13];
  const float* bd     = (const float*)d_in[14];
  const float* vv     = (const float*)d_in[15];
  float* out = (float*)d_out;
  float* W = (float*)d_ws;

  size_t o = 0;
  float* Wt4E = W + o; o += 1048576;
  float* Wt4D = W + o; o += 1048576;
  float* WdT  = W + o; o += 262144;
  float* WihE4 = W + o; o += 2048;
  float* WihD4 = W + o; o += 2048;
  float* bsE4 = W + o; o += 2048;
  float* bsD4 = W + o; o += 2048;
  float* zvec = W + o; o += 512;
  unsigned int* cnt = (unsigned int*)(W + o); o += 32;
  float* cva  = W + o; o += 16384;
  float* vtmp = W + o; o += 15872;
  float* hx   = W + o; o += 65536;
  float* hdec = W + o; o += 65536;
  float* cdec = W + o; o += 32768;
  float* dvec = W + o; o += 32768;
  float* scores = W + o; o += 8192;
  float* e    = W + o; o += 4194304;
  size_t fixed = o;
  float* Mall = W + fixed;
  unsigned short* ehi_u = (unsigned short*)(W + fixed + 8388608);
  unsigned short* elo_u = ehi_u + 4194304;                 // ushort counts
  unsigned short* MhiT  = (unsigned short*)(W + fixed + 8388608 + 4194304);
  unsigned short* MloT  = MhiT + 8388608;

  size_t t3need = (fixed + 3ull * 262144) * 4;
  size_t t2need = (fixed + 32ull * 262144) * 4;
  size_t t1need = (fixed + 32ull * 262144 + 4194304ull + 8388608ull) * 4;
  int tier = (ws_size >= t1need) ? 1 : (ws_size >= t2need) ? 2 : 3;

  k_tpack<<<256, 256, 0, stream>>>(Whh_e, Whh_d, Wt4E, Wt4D);
  k_tr<<<512, 256, 0, stream>>>(We, Wd, Mall, WdT);
  k_small<<<37, 256, 0, stream>>>(Wih_e, Wih_d, bih_e, bhh_e, bih_d, bhh_d, be,
                                  WihE4, WihD4, bsE4, bsD4, zvec, cnt, cva);
  k_enc<<<256, 512, 0, stream>>>(seq, seq_m, WihE4, Wt4E, bsE4, e, hdec, cdec, hx, cnt);

  if (tier == 1) {
    k_packE<<<4096, 256, 0, stream>>>(e, ehi_u, elo_u);
    for (int r = 0; r < 5; ++r) {
      int p = 1 << r;
      dim3 gp(4, 4, p);
      k_gemm<<<gp, 256, 0, stream>>>(Mall, Mall + (size_t)(p - 1) * 262144, zvec,
                                     Mall + (size_t)p * 262144, 262144, 0, 0, 262144);
    }
    k_cvec<<<31, 256, 0, stream>>>(be, Mall, vtmp);
    k_cpref<<<1, 512, 0, stream>>>(be, vtmp, cva);
    k_packM<<<dim3(256, 32), 256, 0, stream>>>(Mall, MhiT, MloT);
    for (int i = 0; i < TN; ++i) {
      float* hr = hdec + (size_t)(i & 1) * 32768;
      float* hw = hdec + (size_t)((i & 1) ^ 1) * 32768;
      k_dstep<<<256, 256, 0, stream>>>(i, target, seq, scores, Wt4D, WihD4, bsD4,
                                       hr, hw, cdec, out);
      k_dproj<<<256, 256, 0, stream>>>(hw, WdT, bd, dvec);
      k_score_mfma<<<256, 256, 0, stream>>>(ehi_u, elo_u,
                                            MhiT + (size_t)i * 262144,
                                            MloT + (size_t)i * 262144,
                                            cva + (size_t)i * 512, dvec, vv, scores);
    }
  } else if (tier == 2) {
    for (int r = 0; r < 5; ++r) {
      int p = 1 << r;
      dim3 gp(4, 4, p);
      k_gemm<<<gp, 256, 0, stream>>>(Mall, Mall + (size_t)(p - 1) * 262144, zvec,
                                     Mall + (size_t)p * 262144, 262144, 0, 0, 262144);
    }
    k_cvec<<<31, 256, 0, stream>>>(be, Mall, vtmp);
    k_cpref<<<1, 512, 0, stream>>>(be, vtmp, cva);
    for (int i = 0; i < TN; ++i) {
      float* hr = hdec + (size_t)(i & 1) * 32768;
      float* hw = hdec + (size_t)((i & 1) ^ 1) * 32768;
      k_dstep<<<256, 256, 0, stream>>>(i, target, seq, scores, Wt4D, WihD4, bsD4,
                                       hr, hw, cdec, out);
      k_dproj<<<256, 256, 0, stream>>>(hw, WdT, bd, dvec);
      k_score<<<512, 256, 0, stream>>>(e, Mall + (size_t)i * 262144,
                                       cva + (size_t)i * 512, dvec, vv, scores);
    }
  } else {
    for (int i = 0; i < TN; ++i) {
      const float* Mi; const float* ci;
      if (i == 0) { Mi = Mall; ci = cva; }
      else {
        float* Msrc = (i == 1) ? Mall : Mall + (size_t)(1 + (i & 1)) * 262144;
        float* Mdst = Mall + (size_t)(1 + ((i - 1) & 1)) * 262144;
        dim3 gp(4, 4, 1);
        k_gemm<<<gp, 256, 0, stream>>>(Msrc, Mall, zvec, Mdst, 0, 0, 0, 0);
        k_cstep<<<1, 512, 0, stream>>>(cva + (size_t)((i - 1) & 1) * 512, Mall, be,
                                       cva + (size_t)(i & 1) * 512);
        Mi = Mdst; ci = cva + (size_t)(i & 1) * 512;
      }
      float* hr = hdec + (size_t)(i & 1) * 32768;
      float* hw = hdec + (size_t)((i & 1) ^ 1) * 32768;
      k_dstep<<<256, 256, 0, stream>>>(i, target, seq, scores, Wt4D, WihD4, bsD4,
                                       hr, hw, cdec, out);
      k_dproj<<<256, 256, 0, stream>>>(hw, WdT, bd, dvec);
      k_score<<<512, 256, 0, stream>>>(e, Mi, ci, dvec, vv, scores);
    }
  }
  k_fin<<<64, 64, 0, stream>>>(scores, seq, out);
}